// Round 3
// baseline (878.641 us; speedup 1.0000x reference)
//
#include <hip/hip_runtime.h>
#include <hip/hip_bf16.h>

// IRChannelAttention on MI355X. Round 3: fp32 global I/O (per reference dtype),
// bf16 workspace intermediates, VALU flash attention.
// B=2, C=64, H=W=80, N=6400.
//
//   setup_fold : fold BN/conv chains into fp32 matrices (transposed [ci][co]) in ws
//   pool_low   : low = 0.5*(maxpool3 + maxpool5)           -> ws bf16 [b][c][n]
//   qkv_kernel : Q,K,V via folded 64x64 matmuls            -> ws bf16 [b][c][n]
//   attn_kernel: flash attention (64-query tile x 100 key tiles) + out conv + residual

#define BATCH 2
#define CH 64
#define HH 80
#define WW 80
#define NN 6400
#define NT 100          // NN / 64
#define EPSV 1e-5f
#define NEGBIG (-1e30f)

typedef __hip_bfloat16 bf16;
__device__ __forceinline__ float b2f(bf16 v){ return __bfloat162float(v); }
__device__ __forceinline__ bf16 f2b(float v){ return __float2bfloat16(v); }

// ws layout: fp32 folded weights, then bf16 arrays
#define OFF_WQ 0          // 4096 fp32, WQ' transposed [ci][co], BN scale folded, block-diag
#define OFF_A1 4096       // 4096 fp32, (kf[:, :32] @ khf) transposed
#define OFF_A2 8192       // 4096 fp32, (kf[:, 32:] @ klf) transposed
#define OFF_WV 12288      // 4096 fp32, (v_w * vscale[ci]) transposed
#define OFF_BQ 16384
#define OFF_BK 16448
#define OFF_BV 16512
#define FOLD_FLOATS 16576
#define OFF_LOW_B (FOLD_FLOATS*4)
#define OFF_Q_B   (OFF_LOW_B + BATCH*CH*NN*2)
#define OFF_K_B   (OFF_Q_B   + BATCH*CH*NN*2)
#define OFF_V_B   (OFF_K_B   + BATCH*CH*NN*2)
// total ws use: ~6.6 MB

__global__ __launch_bounds__(256) void setup_fold(
    const float* __restrict__ q1w, const float* __restrict__ q1g, const float* __restrict__ q1b,
    const float* __restrict__ q2w, const float* __restrict__ q2g, const float* __restrict__ q2b,
    const float* __restrict__ q3w, const float* __restrict__ q3g, const float* __restrict__ q3b,
    const float* __restrict__ khw, const float* __restrict__ khb,
    const float* __restrict__ klw, const float* __restrict__ klb,
    const float* __restrict__ kfw, const float* __restrict__ kfb,
    const float* __restrict__ vg,  const float* __restrict__ vbnb,
    const float* __restrict__ vw,  const float* __restrict__ vb,
    float* __restrict__ wsf)
{
  int tid = threadIdx.x;
  float rs = rsqrtf(1.0f + EPSV);   // BN eval scale denom (running_var=1)
  for (int o = tid; o < 4096; o += 256) {
    int ci = o >> 6, co = o & 63;   // stored transposed: wsf[off + ci*64 + co]
    // Q: block-diagonal grouped conv, BN scale folded into weight
    float w = 0.f, g;
    if (co < 21)      { g = q1g[co];    if (ci < 21)               w = q1w[co*21 + ci]; }
    else if (co < 42) { g = q2g[co-21]; if (ci >= 21 && ci < 42)   w = q2w[(co-21)*21 + (ci-21)]; }
    else              { g = q3g[co-42]; if (ci >= 42)              w = q3w[(co-42)*22 + (ci-42)]; }
    wsf[OFF_WQ + o] = w * g * rs;
    // K composite: K = A1@(x-low) + A2@low + bK
    float a1 = 0.f, a2 = 0.f;
    for (int j = 0; j < 32; ++j) {
      a1 += kfw[co*64 + j]      * khw[j*64 + ci];
      a2 += kfw[co*64 + 32 + j] * klw[j*64 + ci];
    }
    wsf[OFF_A1 + o] = a1;
    wsf[OFF_A2 + o] = a2;
    // V: BN affine folded: V = (vw * vscale[ci]) @ x + (vw@vbias + vb)
    wsf[OFF_WV + o] = vw[co*64 + ci] * vg[ci] * rs;
  }
  if (tid < 64) {
    int co = tid;
    float bq;
    if (co < 21)      bq = q1b[co];
    else if (co < 42) bq = q2b[co-21];
    else              bq = q3b[co-42];
    wsf[OFF_BQ + co] = bq;
    float bk = kfb[co];
    for (int j = 0; j < 32; ++j) {
      bk += kfw[co*64 + j]      * khb[j];
      bk += kfw[co*64 + 32 + j] * klb[j];
    }
    wsf[OFF_BK + co] = bk;
    float bv = vb[co];
    for (int ci = 0; ci < 64; ++ci) bv += vw[co*64 + ci] * vbnb[ci];
    wsf[OFF_BV + co] = bv;
  }
}

__global__ __launch_bounds__(256) void pool_low(const float* __restrict__ x,
                                                bf16* __restrict__ lowg)
{
  int t = blockIdx.x * 256 + threadIdx.x;
  if (t >= BATCH*CH*NN) return;
  int n = t % NN; int bc = t / NN;
  int h = n / WW, w = n % WW;
  const float* p = x + bc*NN;
  float m3 = NEGBIG, m5 = NEGBIG;   // finite init: no inf under fast-math
  #pragma unroll
  for (int dh = -2; dh <= 2; ++dh) {
    int hh = h + dh; if (hh < 0 || hh >= HH) continue;
    #pragma unroll
    for (int dw = -2; dw <= 2; ++dw) {
      int w2 = w + dw; if (w2 < 0 || w2 >= WW) continue;
      float v = p[hh*WW + w2];
      m5 = fmaxf(m5, v);
      if (dh >= -1 && dh <= 1 && dw >= -1 && dw <= 1) m3 = fmaxf(m3, v);
    }
  }
  lowg[t] = f2b(0.5f*(m3 + m5));
}

// One block per (b, 64-position tile). Thread owns one output channel co=tid&63
// for 16 consecutive positions (pg=tid>>6). Weights broadcast from LDS
// (transposed [ci][co] -> stride-1 across lanes, conflict-free).
__global__ __launch_bounds__(256) void qkv_kernel(
    const float* __restrict__ x, const float* __restrict__ wsf,
    const bf16* __restrict__ lowg,
    bf16* __restrict__ qg, bf16* __restrict__ kg, bf16* __restrict__ vgp)
{
  __shared__ __align__(16) float xs[64][64];     // [ci][p]
  __shared__ __align__(16) float lows[64][64];
  __shared__ __align__(16) float wbuf[4096];
  __shared__ float bbuf[64];

  int tid = threadIdx.x;
  int blk = blockIdx.x;
  int b = blk / NT, tile = blk % NT;
  int n0 = tile * 64;
  int co = tid & 63, pg = tid >> 6;

  for (int i = 0; i < 16; ++i) {
    int e = i*256 + tid; int c = e >> 6, p = e & 63;
    xs[c][p]   = x[(b*CH + c)*NN + n0 + p];
    lows[c][p] = b2f(lowg[(b*CH + c)*NN + n0 + p]);
  }

  // ---- Q ----
  for (int i = 0; i < 16; ++i) wbuf[i*256+tid] = wsf[OFF_WQ + i*256 + tid];
  if (tid < 64) bbuf[tid] = wsf[OFF_BQ + tid];
  __syncthreads();
  {
    float bq = bbuf[co];
    float4 acc[4];
    #pragma unroll
    for (int q=0;q<4;++q) acc[q] = make_float4(bq,bq,bq,bq);
    for (int ci = 0; ci < 64; ++ci) {
      float wv = wbuf[ci*64 + co];
      const float4* xr = (const float4*)&xs[ci][0];
      #pragma unroll
      for (int q=0;q<4;++q) {
        float4 xv = xr[pg*4+q];
        acc[q].x += wv*xv.x; acc[q].y += wv*xv.y; acc[q].z += wv*xv.z; acc[q].w += wv*xv.w;
      }
    }
    bf16* dst = qg + (b*CH + co)*NN + n0 + pg*16;
    #pragma unroll
    for (int q=0;q<4;++q) {
      dst[q*4+0] = f2b(fmaxf(acc[q].x,0.f)); dst[q*4+1] = f2b(fmaxf(acc[q].y,0.f));
      dst[q*4+2] = f2b(fmaxf(acc[q].z,0.f)); dst[q*4+3] = f2b(fmaxf(acc[q].w,0.f));
    }
  }
  // ---- V ----
  __syncthreads();
  for (int i = 0; i < 16; ++i) wbuf[i*256+tid] = wsf[OFF_WV + i*256 + tid];
  if (tid < 64) bbuf[tid] = wsf[OFF_BV + tid];
  __syncthreads();
  {
    float bv = bbuf[co];
    float4 acc[4];
    #pragma unroll
    for (int q=0;q<4;++q) acc[q] = make_float4(bv,bv,bv,bv);
    for (int ci = 0; ci < 64; ++ci) {
      float wv = wbuf[ci*64 + co];
      const float4* xr = (const float4*)&xs[ci][0];
      #pragma unroll
      for (int q=0;q<4;++q) {
        float4 xv = xr[pg*4+q];
        acc[q].x += wv*xv.x; acc[q].y += wv*xv.y; acc[q].z += wv*xv.z; acc[q].w += wv*xv.w;
      }
    }
    bf16* dst = vgp + (b*CH + co)*NN + n0 + pg*16;
    #pragma unroll
    for (int q=0;q<4;++q) {
      dst[q*4+0] = f2b(acc[q].x); dst[q*4+1] = f2b(acc[q].y);
      dst[q*4+2] = f2b(acc[q].z); dst[q*4+3] = f2b(acc[q].w);
    }
  }
  // ---- K (two passes: A1@(x-low), A2@low) ----
  __syncthreads();
  for (int i = 0; i < 16; ++i) wbuf[i*256+tid] = wsf[OFF_A1 + i*256 + tid];
  if (tid < 64) bbuf[tid] = wsf[OFF_BK + tid];
  __syncthreads();
  float4 acck[4];
  {
    float bk = bbuf[co];
    #pragma unroll
    for (int q=0;q<4;++q) acck[q] = make_float4(bk,bk,bk,bk);
    for (int ci = 0; ci < 64; ++ci) {
      float wv = wbuf[ci*64 + co];
      const float4* xr = (const float4*)&xs[ci][0];
      const float4* lr = (const float4*)&lows[ci][0];
      #pragma unroll
      for (int q=0;q<4;++q) {
        float4 xv = xr[pg*4+q], lv = lr[pg*4+q];
        acck[q].x += wv*(xv.x-lv.x); acck[q].y += wv*(xv.y-lv.y);
        acck[q].z += wv*(xv.z-lv.z); acck[q].w += wv*(xv.w-lv.w);
      }
    }
  }
  __syncthreads();
  for (int i = 0; i < 16; ++i) wbuf[i*256+tid] = wsf[OFF_A2 + i*256 + tid];
  __syncthreads();
  {
    for (int ci = 0; ci < 64; ++ci) {
      float wv = wbuf[ci*64 + co];
      const float4* lr = (const float4*)&lows[ci][0];
      #pragma unroll
      for (int q=0;q<4;++q) {
        float4 lv = lr[pg*4+q];
        acck[q].x += wv*lv.x; acck[q].y += wv*lv.y; acck[q].z += wv*lv.z; acck[q].w += wv*lv.w;
      }
    }
    bf16* dst = kg + (b*CH + co)*NN + n0 + pg*16;
    #pragma unroll
    for (int q=0;q<4;++q) {
      dst[q*4+0] = f2b(acck[q].x); dst[q*4+1] = f2b(acck[q].y);
      dst[q*4+2] = f2b(acck[q].z); dst[q*4+3] = f2b(acck[q].w);
    }
  }
}

// Flash attention: one block per (b, 64-query tile). Thread (ty=tid>>4, tx=tid&15)
// owns S[n=ty*4+i][m=tx+16j] and O[n=ty*4+i][c=tx+16j] 4x4 register tiles.
// Softmax stats (m,l) live in registers, replicated across the 16 lanes owning
// each row (butterfly reductions give identical values on all 16 lanes).
__global__ __launch_bounds__(256) void attn_kernel(
    const bf16* __restrict__ qg, const bf16* __restrict__ kg, const bf16* __restrict__ vgp,
    const float* __restrict__ x, const float* __restrict__ outw, const float* __restrict__ outb,
    float* __restrict__ out)
{
  __shared__ __align__(16) float Qs[64*68];   // [n][c], later Os [n][c]
  __shared__ __align__(16) float KPs[64*68];  // K tile [m][c] -> P tile [n][m] -> Wot [c][co]
  __shared__ __align__(16) float Vs[64*68];   // [c][m]

  int tid = threadIdx.x;
  int blk = blockIdx.x;
  int b = blk / NT, tile = blk % NT;
  int n0 = tile*64;
  int tx = tid & 15, ty = tid >> 4;

  for (int i = 0; i < 16; ++i) {
    int e = i*256 + tid; int c = e >> 6, nn = e & 63;
    Qs[nn*68 + c] = b2f(qg[(b*CH + c)*NN + n0 + nn]);
  }

  float m_run[4], l_run[4];
  float O[4][4];
  #pragma unroll
  for (int i=0;i<4;++i) {
    m_run[i] = NEGBIG; l_run[i] = 0.f;
    #pragma unroll
    for (int j=0;j<4;++j) O[i][j]=0.f;
  }

  for (int mt = 0; mt < NT; ++mt) {
    int m0 = mt*64;
    __syncthreads();   // prev PV done with KPs/Vs (iter0: Qs writes done)
    for (int i = 0; i < 16; ++i) {
      int e = i*256 + tid; int c = e >> 6, mm = e & 63;
      KPs[mm*68 + c] = b2f(kg[(b*CH + c)*NN + m0 + mm]);
      Vs[c*68 + mm]  = b2f(vgp[(b*CH + c)*NN + m0 + mm]);
    }
    __syncthreads();

    // S = (Q K^T)/8
    float S[4][4];
    #pragma unroll
    for (int i=0;i<4;++i)
      #pragma unroll
      for (int j=0;j<4;++j) S[i][j]=0.f;
    for (int cs = 0; cs < 16; ++cs) {
      int ci = cs*4;
      float4 qf[4], kf[4];
      #pragma unroll
      for (int i=0;i<4;++i) qf[i] = *(const float4*)&Qs[(ty*4+i)*68 + ci];
      #pragma unroll
      for (int j=0;j<4;++j) kf[j] = *(const float4*)&KPs[(tx+16*j)*68 + ci];
      #pragma unroll
      for (int i=0;i<4;++i)
        #pragma unroll
        for (int j=0;j<4;++j)
          S[i][j] += qf[i].x*kf[j].x + qf[i].y*kf[j].y + qf[i].z*kf[j].z + qf[i].w*kf[j].w;
    }

    // per-row stats in registers (replicated across the 16 owning lanes)
    float mnew[4], alpha[4];
    #pragma unroll
    for (int i=0;i<4;++i) {
      float m = fmaxf(fmaxf(S[i][0],S[i][1]), fmaxf(S[i][2],S[i][3])) * 0.125f;
      m = fmaxf(m, __shfl_xor(m, 8, 16));
      m = fmaxf(m, __shfl_xor(m, 4, 16));
      m = fmaxf(m, __shfl_xor(m, 2, 16));
      m = fmaxf(m, __shfl_xor(m, 1, 16));
      mnew[i]  = fmaxf(m_run[i], m);
      alpha[i] = __expf(m_run[i] - mnew[i]);   // finite-finite, ==0 when m_run=NEGBIG
      m_run[i] = mnew[i];
    }
    __syncthreads();   // all S reads of KPs (K tile) complete before P overwrite

    // P = exp(S/8 - mnew) -> KPs (aliasing K tile); l update in registers
    #pragma unroll
    for (int i=0;i<4;++i) {
      float s = 0.f;
      #pragma unroll
      for (int j=0;j<4;++j) {
        float p = __expf(S[i][j]*0.125f - mnew[i]);
        KPs[(ty*4+i)*68 + tx + 16*j] = p;
        s += p;
      }
      s += __shfl_xor(s, 8, 16);
      s += __shfl_xor(s, 4, 16);
      s += __shfl_xor(s, 2, 16);
      s += __shfl_xor(s, 1, 16);
      l_run[i] = l_run[i]*alpha[i] + s;
    }
    __syncthreads();   // P visible

    // O = alpha*O + P @ V^T
    #pragma unroll
    for (int i=0;i<4;++i)
      #pragma unroll
      for (int j=0;j<4;++j) O[i][j] *= alpha[i];
    for (int ms = 0; ms < 16; ++ms) {
      int m = ms*4;
      float4 pf[4], vf[4];
      #pragma unroll
      for (int i=0;i<4;++i) pf[i] = *(const float4*)&KPs[(ty*4+i)*68 + m];
      #pragma unroll
      for (int j=0;j<4;++j) vf[j] = *(const float4*)&Vs[(tx+16*j)*68 + m];
      #pragma unroll
      for (int i=0;i<4;++i)
        #pragma unroll
        for (int j=0;j<4;++j)
          O[i][j] += pf[i].x*vf[j].x + pf[i].y*vf[j].y + pf[i].z*vf[j].z + pf[i].w*vf[j].w;
    }
  }

  // epilogue: normalize, out conv, residual
  __syncthreads();
  #pragma unroll
  for (int i=0;i<4;++i) {
    float linv = 1.0f / l_run[i];
    #pragma unroll
    for (int j=0;j<4;++j)
      Qs[(ty*4+i)*68 + tx + 16*j] = O[i][j]*linv;   // Os[n][c]
  }
  for (int i = 0; i < 16; ++i) {
    int e = i*256 + tid; int co2 = e >> 6, c = e & 63;
    KPs[c*68 + co2] = outw[co2*64 + c];             // Wot[c][co]
  }
  __syncthreads();
  {
    int n = tid & 63, cog = tid >> 6;
    float acc[16];
    #pragma unroll
    for (int k=0;k<16;++k) acc[k] = outb[cog*16+k];
    for (int c = 0; c < 64; ++c) {
      float ov = Qs[n*68 + c];
      #pragma unroll
      for (int k=0;k<16;++k) acc[k] += KPs[c*68 + cog*16 + k] * ov;
    }
    #pragma unroll
    for (int k=0;k<16;++k) {
      int co2 = cog*16 + k;
      int idx = (b*CH + co2)*NN + n0 + n;
      out[idx] = acc[k] + x[idx];
    }
  }
}

extern "C" void kernel_launch(void* const* d_in, const int* in_sizes, int n_in,
                              void* d_out, int out_size, void* d_ws, size_t ws_size,
                              hipStream_t stream) {
  const float* x    = (const float*)d_in[0];
  const float* q1w  = (const float*)d_in[1];
  const float* q1g  = (const float*)d_in[2];
  const float* q1b  = (const float*)d_in[3];
  const float* q2w  = (const float*)d_in[4];
  const float* q2g  = (const float*)d_in[5];
  const float* q2b  = (const float*)d_in[6];
  const float* q3w  = (const float*)d_in[7];
  const float* q3g  = (const float*)d_in[8];
  const float* q3b  = (const float*)d_in[9];
  const float* khw  = (const float*)d_in[10];
  const float* khb  = (const float*)d_in[11];
  const float* klw  = (const float*)d_in[12];
  const float* klb  = (const float*)d_in[13];
  const float* kfw  = (const float*)d_in[14];
  const float* kfb  = (const float*)d_in[15];
  const float* vbg  = (const float*)d_in[16];
  const float* vbb  = (const float*)d_in[17];
  const float* vw   = (const float*)d_in[18];
  const float* vb   = (const float*)d_in[19];
  const float* outw = (const float*)d_in[20];
  const float* outb = (const float*)d_in[21];

  float* wsf = (float*)d_ws;
  char*  wsb = (char*)d_ws;
  bf16* lowg = (bf16*)(wsb + OFF_LOW_B);
  bf16* qgp  = (bf16*)(wsb + OFF_Q_B);
  bf16* kgp  = (bf16*)(wsb + OFF_K_B);
  bf16* vgp  = (bf16*)(wsb + OFF_V_B);

  hipLaunchKernelGGL(setup_fold, dim3(1), dim3(256), 0, stream,
                     q1w,q1g,q1b,q2w,q2g,q2b,q3w,q3g,q3b,
                     khw,khb,klw,klb,kfw,kfb,vbg,vbb,vw,vb, wsf);
  hipLaunchKernelGGL(pool_low, dim3((BATCH*CH*NN)/256), dim3(256), 0, stream, x, lowg);
  hipLaunchKernelGGL(qkv_kernel, dim3(BATCH*NT), dim3(256), 0, stream,
                     x, wsf, lowg, qgp, kgp, vgp);
  hipLaunchKernelGGL(attn_kernel, dim3(BATCH*NT), dim3(256), 0, stream,
                     qgp, kgp, vgp, x, outw, outb, (float*)d_out);
}

// Round 4
// 388.932 us; speedup vs baseline: 2.2591x; 2.2591x over previous
//
#include <hip/hip_runtime.h>
#include <hip/hip_bf16.h>

// IRChannelAttention on MI355X. Round 4: MFMA flash attention.
// B=2, C=64, H=W=80, N=6400. fp32 global I/O, bf16 ws intermediates.
//
//   setup_fold : fold BN/conv chains into fp32 matrices in ws
//   pool_low   : low = 0.5*(maxpool3 + maxpool5)        -> ws bf16 [b][c][n]
//   qkv_kernel : Q,K -> ws bf16 [b][n][c] (transposed, coalesced + MFMA-ready),
//                V   -> ws bf16 [b][c][n]
//   attn_kernel: mfma_f32_16x16x32_bf16 flash attention + out conv + residual

#define BATCH 2
#define CH 64
#define HH 80
#define WW 80
#define NN 6400
#define NT 100          // NN / 64
#define EPSV 1e-5f
#define NEGBIG (-1e30f)
#define QP 72           // bf16 LDS tile pitch (144 B rows: bank-rotating, 16B-aligned)
#define OP 68           // fp32 epilogue pitch

typedef __hip_bfloat16 bf16;
typedef __attribute__((ext_vector_type(8))) short short8;   // 8 bf16 = 4 VGPR (MFMA A/B frag)
typedef __attribute__((ext_vector_type(4))) float f4;       // MFMA C/D frag
#define MFMA16 __builtin_amdgcn_mfma_f32_16x16x32_bf16

__device__ __forceinline__ float b2f(bf16 v){ return __bfloat162float(v); }
__device__ __forceinline__ bf16 f2b(float v){ return __float2bfloat16(v); }

// ws layout: fp32 folded weights, then bf16 arrays
#define OFF_WQ 0
#define OFF_A1 4096
#define OFF_A2 8192
#define OFF_WV 12288
#define OFF_BQ 16384
#define OFF_BK 16448
#define OFF_BV 16512
#define FOLD_FLOATS 16576
#define OFF_LOW_B (FOLD_FLOATS*4)
#define OFF_Q_B   (OFF_LOW_B + BATCH*CH*NN*2)   // qgT [b][n][c]
#define OFF_K_B   (OFF_Q_B   + BATCH*CH*NN*2)   // kgT [b][n][c]
#define OFF_V_B   (OFF_K_B   + BATCH*CH*NN*2)   // vg  [b][c][n]

__global__ __launch_bounds__(256) void setup_fold(
    const float* __restrict__ q1w, const float* __restrict__ q1g, const float* __restrict__ q1b,
    const float* __restrict__ q2w, const float* __restrict__ q2g, const float* __restrict__ q2b,
    const float* __restrict__ q3w, const float* __restrict__ q3g, const float* __restrict__ q3b,
    const float* __restrict__ khw, const float* __restrict__ khb,
    const float* __restrict__ klw, const float* __restrict__ klb,
    const float* __restrict__ kfw, const float* __restrict__ kfb,
    const float* __restrict__ vg,  const float* __restrict__ vbnb,
    const float* __restrict__ vw,  const float* __restrict__ vb,
    float* __restrict__ wsf)
{
  int tid = threadIdx.x;
  float rs = rsqrtf(1.0f + EPSV);
  for (int o = tid; o < 4096; o += 256) {
    int ci = o >> 6, co = o & 63;   // stored transposed: wsf[off + ci*64 + co]
    float w = 0.f, g;
    if (co < 21)      { g = q1g[co];    if (ci < 21)               w = q1w[co*21 + ci]; }
    else if (co < 42) { g = q2g[co-21]; if (ci >= 21 && ci < 42)   w = q2w[(co-21)*21 + (ci-21)]; }
    else              { g = q3g[co-42]; if (ci >= 42)              w = q3w[(co-42)*22 + (ci-42)]; }
    wsf[OFF_WQ + o] = w * g * rs;
    float a1 = 0.f, a2 = 0.f;
    for (int j = 0; j < 32; ++j) {
      a1 += kfw[co*64 + j]      * khw[j*64 + ci];
      a2 += kfw[co*64 + 32 + j] * klw[j*64 + ci];
    }
    wsf[OFF_A1 + o] = a1;
    wsf[OFF_A2 + o] = a2;
    wsf[OFF_WV + o] = vw[co*64 + ci] * vg[ci] * rs;
  }
  if (tid < 64) {
    int co = tid;
    float bq;
    if (co < 21)      bq = q1b[co];
    else if (co < 42) bq = q2b[co-21];
    else              bq = q3b[co-42];
    wsf[OFF_BQ + co] = bq;
    float bk = kfb[co];
    for (int j = 0; j < 32; ++j) {
      bk += kfw[co*64 + j]      * khb[j];
      bk += kfw[co*64 + 32 + j] * klb[j];
    }
    wsf[OFF_BK + co] = bk;
    float bv = vb[co];
    for (int ci = 0; ci < 64; ++ci) bv += vw[co*64 + ci] * vbnb[ci];
    wsf[OFF_BV + co] = bv;
  }
}

__global__ __launch_bounds__(256) void pool_low(const float* __restrict__ x,
                                                bf16* __restrict__ lowg)
{
  int t = blockIdx.x * 256 + threadIdx.x;
  if (t >= BATCH*CH*NN) return;
  int n = t % NN; int bc = t / NN;
  int h = n / WW, w = n % WW;
  const float* p = x + bc*NN;
  float m3 = NEGBIG, m5 = NEGBIG;
  #pragma unroll
  for (int dh = -2; dh <= 2; ++dh) {
    int hh = h + dh; if (hh < 0 || hh >= HH) continue;
    #pragma unroll
    for (int dw = -2; dw <= 2; ++dw) {
      int w2 = w + dw; if (w2 < 0 || w2 >= WW) continue;
      float v = p[hh*WW + w2];
      m5 = fmaxf(m5, v);
      if (dh >= -1 && dh <= 1 && dw >= -1 && dw <= 1) m3 = fmaxf(m3, v);
    }
  }
  lowg[t] = f2b(0.5f*(m3 + m5));
}

// One block per (b, 64-position tile). Thread owns channel co=tid&63 for 16
// positions (pg=tid>>6). Q,K written transposed [n][c] (coalesced: lanes span
// co, contiguous 128B per position). V written [c][n] (as before).
__global__ __launch_bounds__(256) void qkv_kernel(
    const float* __restrict__ x, const float* __restrict__ wsf,
    const bf16* __restrict__ lowg,
    bf16* __restrict__ qgT, bf16* __restrict__ kgT, bf16* __restrict__ vgp)
{
  __shared__ __align__(16) float xs[64][64];     // [ci][p]
  __shared__ __align__(16) float lows[64][64];
  __shared__ __align__(16) float wbuf[4096];
  __shared__ float bbuf[64];

  int tid = threadIdx.x;
  int blk = blockIdx.x;
  int b = blk / NT, tile = blk % NT;
  int n0 = tile * 64;
  int co = tid & 63, pg = tid >> 6;

  for (int i = 0; i < 16; ++i) {
    int e = i*256 + tid; int c = e >> 6, p = e & 63;
    xs[c][p]   = x[(b*CH + c)*NN + n0 + p];
    lows[c][p] = b2f(lowg[(b*CH + c)*NN + n0 + p]);
  }

  // ---- Q ----
  for (int i = 0; i < 16; ++i) wbuf[i*256+tid] = wsf[OFF_WQ + i*256 + tid];
  if (tid < 64) bbuf[tid] = wsf[OFF_BQ + tid];
  __syncthreads();
  {
    float bq = bbuf[co];
    float4 acc[4];
    #pragma unroll
    for (int q=0;q<4;++q) acc[q] = make_float4(bq,bq,bq,bq);
    for (int ci = 0; ci < 64; ++ci) {
      float wv = wbuf[ci*64 + co];
      const float4* xr = (const float4*)&xs[ci][0];
      #pragma unroll
      for (int q=0;q<4;++q) {
        float4 xv = xr[pg*4+q];
        acc[q].x += wv*xv.x; acc[q].y += wv*xv.y; acc[q].z += wv*xv.z; acc[q].w += wv*xv.w;
      }
    }
    bf16* dq = qgT + ((size_t)(b*NN + n0 + pg*16))*64 + co;
    #pragma unroll
    for (int q=0;q<4;++q) {
      dq[(q*4+0)*64] = f2b(fmaxf(acc[q].x,0.f)); dq[(q*4+1)*64] = f2b(fmaxf(acc[q].y,0.f));
      dq[(q*4+2)*64] = f2b(fmaxf(acc[q].z,0.f)); dq[(q*4+3)*64] = f2b(fmaxf(acc[q].w,0.f));
    }
  }
  // ---- V ----
  __syncthreads();
  for (int i = 0; i < 16; ++i) wbuf[i*256+tid] = wsf[OFF_WV + i*256 + tid];
  if (tid < 64) bbuf[tid] = wsf[OFF_BV + tid];
  __syncthreads();
  {
    float bv = bbuf[co];
    float4 acc[4];
    #pragma unroll
    for (int q=0;q<4;++q) acc[q] = make_float4(bv,bv,bv,bv);
    for (int ci = 0; ci < 64; ++ci) {
      float wv = wbuf[ci*64 + co];
      const float4* xr = (const float4*)&xs[ci][0];
      #pragma unroll
      for (int q=0;q<4;++q) {
        float4 xv = xr[pg*4+q];
        acc[q].x += wv*xv.x; acc[q].y += wv*xv.y; acc[q].z += wv*xv.z; acc[q].w += wv*xv.w;
      }
    }
    bf16* dst = vgp + (b*CH + co)*NN + n0 + pg*16;
    #pragma unroll
    for (int q=0;q<4;++q) {
      dst[q*4+0] = f2b(acc[q].x); dst[q*4+1] = f2b(acc[q].y);
      dst[q*4+2] = f2b(acc[q].z); dst[q*4+3] = f2b(acc[q].w);
    }
  }
  // ---- K (two passes: A1@(x-low), A2@low) ----
  __syncthreads();
  for (int i = 0; i < 16; ++i) wbuf[i*256+tid] = wsf[OFF_A1 + i*256 + tid];
  if (tid < 64) bbuf[tid] = wsf[OFF_BK + tid];
  __syncthreads();
  float4 acck[4];
  {
    float bk = bbuf[co];
    #pragma unroll
    for (int q=0;q<4;++q) acck[q] = make_float4(bk,bk,bk,bk);
    for (int ci = 0; ci < 64; ++ci) {
      float wv = wbuf[ci*64 + co];
      const float4* xr = (const float4*)&xs[ci][0];
      const float4* lr = (const float4*)&lows[ci][0];
      #pragma unroll
      for (int q=0;q<4;++q) {
        float4 xv = xr[pg*4+q], lv = lr[pg*4+q];
        acck[q].x += wv*(xv.x-lv.x); acck[q].y += wv*(xv.y-lv.y);
        acck[q].z += wv*(xv.z-lv.z); acck[q].w += wv*(xv.w-lv.w);
      }
    }
  }
  __syncthreads();
  for (int i = 0; i < 16; ++i) wbuf[i*256+tid] = wsf[OFF_A2 + i*256 + tid];
  __syncthreads();
  {
    for (int ci = 0; ci < 64; ++ci) {
      float wv = wbuf[ci*64 + co];
      const float4* lr = (const float4*)&lows[ci][0];
      #pragma unroll
      for (int q=0;q<4;++q) {
        float4 lv = lr[pg*4+q];
        acck[q].x += wv*lv.x; acck[q].y += wv*lv.y; acck[q].z += wv*lv.z; acck[q].w += wv*lv.w;
      }
    }
    bf16* dk = kgT + ((size_t)(b*NN + n0 + pg*16))*64 + co;
    #pragma unroll
    for (int q=0;q<4;++q) {
      dk[(q*4+0)*64] = f2b(acck[q].x); dk[(q*4+1)*64] = f2b(acck[q].y);
      dk[(q*4+2)*64] = f2b(acck[q].z); dk[(q*4+3)*64] = f2b(acck[q].w);
    }
  }
}

// MFMA flash attention. One block per (b, 64-query tile); 4 waves, wave wv owns
// query strip n in [wv*16, wv*16+16).
// A/B frag: lane&15 = row, k = quad*8+j (b128 from [row][64] bf16, pitch 72).
// C/D frag: col = lane&15, row = quad*4+reg.
// S: A=Q rows [n][c], B=K rows [m][c] -> S[n=quad*4+reg][m=lane&15].
// P -> LDS [n][m] (wave-local, in-order DS => no barrier).
// PV: A=P rows [n][m], B=V rows [c][m] -> O[n=quad*4+reg][c=lane&15].
__global__ __launch_bounds__(256) void attn_kernel(
    const bf16* __restrict__ qgT, const bf16* __restrict__ kgT, const bf16* __restrict__ vgp,
    const float* __restrict__ x, const float* __restrict__ outw, const float* __restrict__ outb,
    float* __restrict__ out)
{
  __shared__ __align__(16) char smem[36864];
  bf16* Qld = (bf16*)smem;              // [64][QP]
  bf16* Kld = (bf16*)(smem + 9216);     // [64][QP]  (m rows)
  bf16* Vld = (bf16*)(smem + 18432);    // [64][QP]  (c rows)
  bf16* Pld = (bf16*)(smem + 27648);    // [64][QP]  (n rows)
  float* Os  = (float*)smem;            // epilogue alias over Q+K: [64][OP]
  float* Wot = (float*)(smem + 18432);  // epilogue alias over V+P: [64][OP]

  int tid = threadIdx.x;
  int b = blockIdx.x / NT, tile = blockIdx.x % NT;
  int n0 = tile*64;
  int wv = tid >> 6, lane = tid & 63, ln = lane & 15, quad = lane >> 4;
  int arow = (wv*16 + ln)*QP;           // this lane's A-frag row base

  // stage Q [n][c]
  #pragma unroll
  for (int i = 0; i < 4; ++i) {
    int f = (i*256 + tid)*4; int n = f >> 6, c = f & 63;
    *(uint2*)&Qld[n*QP + c] = *(const uint2*)&qgT[(size_t)(b*NN + n0 + n)*64 + c];
  }

  float m_run[4], l_run[4];
  f4 accO[4];
  #pragma unroll
  for (int r=0;r<4;++r){ m_run[r]=NEGBIG; l_run[r]=0.f; }
  #pragma unroll
  for (int t=0;t<4;++t) accO[t] = (f4){0.f,0.f,0.f,0.f};

  for (int mt = 0; mt < NT; ++mt) {
    int m0 = mt*64;
    __syncthreads();   // prior iter's K/V reads complete
    #pragma unroll
    for (int i = 0; i < 4; ++i) {
      int f = (i*256 + tid)*4; int rr = f >> 6, cc = f & 63;
      *(uint2*)&Kld[rr*QP + cc] = *(const uint2*)&kgT[(size_t)(b*NN + m0 + rr)*64 + cc];
      *(uint2*)&Vld[rr*QP + cc] = *(const uint2*)&vgp[(size_t)(b*CH + rr)*NN + m0 + cc];
    }
    __syncthreads();

    // ---- S = Q K^T (raw; /8 folded into softmax) ----
    short8 aq0 = *(const short8*)&Qld[arow + quad*8];
    short8 aq1 = *(const short8*)&Qld[arow + 32 + quad*8];
    f4 accS[4];
    #pragma unroll
    for (int t = 0; t < 4; ++t) {
      short8 bk0 = *(const short8*)&Kld[(t*16+ln)*QP + quad*8];
      short8 bk1 = *(const short8*)&Kld[(t*16+ln)*QP + 32 + quad*8];
      f4 z = (f4){0.f,0.f,0.f,0.f};
      z = MFMA16(aq0, bk0, z, 0, 0, 0);
      accS[t] = MFMA16(aq1, bk1, z, 0, 0, 0);
    }

    // ---- online softmax (stats per reg r -> row n = wv*16+quad*4+r) ----
    float mnew[4], alpha[4];
    #pragma unroll
    for (int r=0;r<4;++r) {
      float m = fmaxf(fmaxf(accS[0][r],accS[1][r]), fmaxf(accS[2][r],accS[3][r])) * 0.125f;
      m = fmaxf(m, __shfl_xor(m, 1, 16));
      m = fmaxf(m, __shfl_xor(m, 2, 16));
      m = fmaxf(m, __shfl_xor(m, 4, 16));
      m = fmaxf(m, __shfl_xor(m, 8, 16));
      mnew[r]  = fmaxf(m_run[r], m);
      alpha[r] = __expf(m_run[r] - mnew[r]);   // 0 on first tile
      m_run[r] = mnew[r];
    }
    #pragma unroll
    for (int r=0;r<4;++r) {
      int n = wv*16 + quad*4 + r;
      float s = 0.f;
      #pragma unroll
      for (int t=0;t<4;++t) {
        float p = __expf(accS[t][r]*0.125f - mnew[r]);
        Pld[n*QP + t*16 + ln] = f2b(p);
        s += p;
      }
      s += __shfl_xor(s, 1, 16);
      s += __shfl_xor(s, 2, 16);
      s += __shfl_xor(s, 4, 16);
      s += __shfl_xor(s, 8, 16);
      l_run[r] = l_run[r]*alpha[r] + s;
    }

    // ---- O = alpha*O + P V^T (P wave-local: per-wave DS ordering suffices) ----
    f4 al = (f4){alpha[0], alpha[1], alpha[2], alpha[3]};
    #pragma unroll
    for (int t=0;t<4;++t) accO[t] *= al;
    short8 ap0 = *(const short8*)&Pld[arow + quad*8];
    short8 ap1 = *(const short8*)&Pld[arow + 32 + quad*8];
    #pragma unroll
    for (int t = 0; t < 4; ++t) {
      short8 bv0 = *(const short8*)&Vld[(t*16+ln)*QP + quad*8];
      short8 bv1 = *(const short8*)&Vld[(t*16+ln)*QP + 32 + quad*8];
      accO[t] = MFMA16(ap0, bv0, accO[t], 0, 0, 0);
      accO[t] = MFMA16(ap1, bv1, accO[t], 0, 0, 0);
    }
  }

  // ---- epilogue: normalize, out conv, residual ----
  __syncthreads();   // all waves done with K/V/P before alias overwrite
  #pragma unroll
  for (int r=0;r<4;++r) {
    float inv = 1.0f / l_run[r];
    int n = wv*16 + quad*4 + r;
    #pragma unroll
    for (int t=0;t<4;++t) Os[n*OP + t*16 + ln] = accO[t][r] * inv;
  }
  for (int i = 0; i < 16; ++i) {
    int e = i*256 + tid; int co2 = e >> 6, c = e & 63;
    Wot[c*OP + co2] = outw[co2*64 + c];
  }
  __syncthreads();
  {
    int n = tid & 63, cog = tid >> 6;
    float acc[16];
    #pragma unroll
    for (int k=0;k<16;++k) acc[k] = outb[cog*16+k];
    for (int c = 0; c < 64; ++c) {
      float ov = Os[n*OP + c];
      #pragma unroll
      for (int k=0;k<16;++k) acc[k] += Wot[c*OP + cog*16 + k] * ov;
    }
    #pragma unroll
    for (int k=0;k<16;++k) {
      int co2 = cog*16 + k;
      int idx = (b*CH + co2)*NN + n0 + n;
      out[idx] = acc[k] + x[idx];
    }
  }
}

extern "C" void kernel_launch(void* const* d_in, const int* in_sizes, int n_in,
                              void* d_out, int out_size, void* d_ws, size_t ws_size,
                              hipStream_t stream) {
  const float* x    = (const float*)d_in[0];
  const float* q1w  = (const float*)d_in[1];
  const float* q1g  = (const float*)d_in[2];
  const float* q1b  = (const float*)d_in[3];
  const float* q2w  = (const float*)d_in[4];
  const float* q2g  = (const float*)d_in[5];
  const float* q2b  = (const float*)d_in[6];
  const float* q3w  = (const float*)d_in[7];
  const float* q3g  = (const float*)d_in[8];
  const float* q3b  = (const float*)d_in[9];
  const float* khw  = (const float*)d_in[10];
  const float* khb  = (const float*)d_in[11];
  const float* klw  = (const float*)d_in[12];
  const float* klb  = (const float*)d_in[13];
  const float* kfw  = (const float*)d_in[14];
  const float* kfb  = (const float*)d_in[15];
  const float* vbg  = (const float*)d_in[16];
  const float* vbb  = (const float*)d_in[17];
  const float* vw   = (const float*)d_in[18];
  const float* vb   = (const float*)d_in[19];
  const float* outw = (const float*)d_in[20];
  const float* outb = (const float*)d_in[21];

  float* wsf = (float*)d_ws;
  char*  wsb = (char*)d_ws;
  bf16* lowg = (bf16*)(wsb + OFF_LOW_B);
  bf16* qgT  = (bf16*)(wsb + OFF_Q_B);
  bf16* kgT  = (bf16*)(wsb + OFF_K_B);
  bf16* vgp  = (bf16*)(wsb + OFF_V_B);

  hipLaunchKernelGGL(setup_fold, dim3(1), dim3(256), 0, stream,
                     q1w,q1g,q1b,q2w,q2g,q2b,q3w,q3g,q3b,
                     khw,khb,klw,klb,kfw,kfb,vbg,vbb,vw,vb, wsf);
  hipLaunchKernelGGL(pool_low, dim3((BATCH*CH*NN)/256), dim3(256), 0, stream, x, lowg);
  hipLaunchKernelGGL(qkv_kernel, dim3(BATCH*NT), dim3(256), 0, stream,
                     x, wsf, lowg, qgT, kgT, vgp);
  hipLaunchKernelGGL(attn_kernel, dim3(BATCH*NT), dim3(256), 0, stream,
                     qgT, kgT, vgp, x, outw, outb, (float*)d_out);
}

// Round 5
// 317.378 us; speedup vs baseline: 2.7684x; 1.2255x over previous
//
#include <hip/hip_runtime.h>
#include <hip/hip_bf16.h>

// IRChannelAttention on MI355X. Round 5: split-K MFMA flash attention.
// B=2, C=64, H=W=80, N=6400. fp32 global I/O, bf16 ws intermediates.
//
//   setup_fold  : fold BN/conv chains into fp32 matrices in ws
//   pool_low    : low = 0.5*(maxpool3 + maxpool5)        -> ws bf16 [b][c][n]
//   qkv_kernel  : Q,K -> ws bf16 [b][n][c] (transposed), V -> ws bf16 [b][c][n]
//   attn_partial: split-K flash (25 key-tiles per split, KS=4) -> O',m,l in ws
//   attn_reduce : merge splits + out conv + residual

#define BATCH 2
#define CH 64
#define HH 80
#define WW 80
#define NN 6400
#define NT 100          // NN / 64
#define KS 4            // key splits
#define KTPS (NT/KS)    // key tiles per split = 25
#define EPSV 1e-5f
#define NEGBIG (-1e30f)
#define QP 72           // bf16 LDS tile pitch
#define OP 68           // fp32 epilogue pitch

typedef __hip_bfloat16 bf16;
typedef __attribute__((ext_vector_type(8))) short short8;   // 8 bf16 = 4 VGPR (MFMA A/B frag)
typedef __attribute__((ext_vector_type(4))) float f4;       // MFMA C/D frag
#define MFMA16 __builtin_amdgcn_mfma_f32_16x16x32_bf16

__device__ __forceinline__ float b2f(bf16 v){ return __bfloat162float(v); }
__device__ __forceinline__ bf16 f2b(float v){ return __float2bfloat16(v); }

// ws layout: fp32 folded weights, then bf16 arrays, then split-K partials (fp32)
#define OFF_WQ 0
#define OFF_A1 4096
#define OFF_A2 8192
#define OFF_WV 12288
#define OFF_BQ 16384
#define OFF_BK 16448
#define OFF_BV 16512
#define FOLD_FLOATS 16576
#define OFF_LOW_B (FOLD_FLOATS*4)
#define OFF_Q_B   (OFF_LOW_B + BATCH*CH*NN*2)   // qgT [b][n][c]
#define OFF_K_B   (OFF_Q_B   + BATCH*CH*NN*2)   // kgT [b][n][c]
#define OFF_V_B   (OFF_K_B   + BATCH*CH*NN*2)   // vg  [b][c][n]
#define OFF_P_B   (OFF_V_B   + BATCH*CH*NN*2)   // part O' [b*NT+tile][KS][64][64] f32
#define OFF_ML_B  (OFF_P_B   + BATCH*NT*KS*4096*4) // ml [b*NT+tile][KS][2][64] f32
// total ws use: ~20.1 MB

__global__ __launch_bounds__(256) void setup_fold(
    const float* __restrict__ q1w, const float* __restrict__ q1g, const float* __restrict__ q1b,
    const float* __restrict__ q2w, const float* __restrict__ q2g, const float* __restrict__ q2b,
    const float* __restrict__ q3w, const float* __restrict__ q3g, const float* __restrict__ q3b,
    const float* __restrict__ khw, const float* __restrict__ khb,
    const float* __restrict__ klw, const float* __restrict__ klb,
    const float* __restrict__ kfw, const float* __restrict__ kfb,
    const float* __restrict__ vg,  const float* __restrict__ vbnb,
    const float* __restrict__ vw,  const float* __restrict__ vb,
    float* __restrict__ wsf)
{
  int tid = threadIdx.x;
  float rs = rsqrtf(1.0f + EPSV);
  for (int o = tid; o < 4096; o += 256) {
    int ci = o >> 6, co = o & 63;   // stored transposed: wsf[off + ci*64 + co]
    float w = 0.f, g;
    if (co < 21)      { g = q1g[co];    if (ci < 21)               w = q1w[co*21 + ci]; }
    else if (co < 42) { g = q2g[co-21]; if (ci >= 21 && ci < 42)   w = q2w[(co-21)*21 + (ci-21)]; }
    else              { g = q3g[co-42]; if (ci >= 42)              w = q3w[(co-42)*22 + (ci-42)]; }
    wsf[OFF_WQ + o] = w * g * rs;
    float a1 = 0.f, a2 = 0.f;
    for (int j = 0; j < 32; ++j) {
      a1 += kfw[co*64 + j]      * khw[j*64 + ci];
      a2 += kfw[co*64 + 32 + j] * klw[j*64 + ci];
    }
    wsf[OFF_A1 + o] = a1;
    wsf[OFF_A2 + o] = a2;
    wsf[OFF_WV + o] = vw[co*64 + ci] * vg[ci] * rs;
  }
  if (tid < 64) {
    int co = tid;
    float bq;
    if (co < 21)      bq = q1b[co];
    else if (co < 42) bq = q2b[co-21];
    else              bq = q3b[co-42];
    wsf[OFF_BQ + co] = bq;
    float bk = kfb[co];
    for (int j = 0; j < 32; ++j) {
      bk += kfw[co*64 + j]      * khb[j];
      bk += kfw[co*64 + 32 + j] * klb[j];
    }
    wsf[OFF_BK + co] = bk;
    float bv = vb[co];
    for (int ci = 0; ci < 64; ++ci) bv += vw[co*64 + ci] * vbnb[ci];
    wsf[OFF_BV + co] = bv;
  }
}

__global__ __launch_bounds__(256) void pool_low(const float* __restrict__ x,
                                                bf16* __restrict__ lowg)
{
  int t = blockIdx.x * 256 + threadIdx.x;
  if (t >= BATCH*CH*NN) return;
  int n = t % NN; int bc = t / NN;
  int h = n / WW, w = n % WW;
  const float* p = x + bc*NN;
  float m3 = NEGBIG, m5 = NEGBIG;
  #pragma unroll
  for (int dh = -2; dh <= 2; ++dh) {
    int hh = h + dh; if (hh < 0 || hh >= HH) continue;
    #pragma unroll
    for (int dw = -2; dw <= 2; ++dw) {
      int w2 = w + dw; if (w2 < 0 || w2 >= WW) continue;
      float v = p[hh*WW + w2];
      m5 = fmaxf(m5, v);
      if (dh >= -1 && dh <= 1 && dw >= -1 && dw <= 1) m3 = fmaxf(m3, v);
    }
  }
  lowg[t] = f2b(0.5f*(m3 + m5));
}

// One block per (b, 64-position tile). Thread owns channel co=tid&63 for 16
// positions (pg=tid>>6). Q,K written transposed [n][c]; V written [c][n].
__global__ __launch_bounds__(256) void qkv_kernel(
    const float* __restrict__ x, const float* __restrict__ wsf,
    const bf16* __restrict__ lowg,
    bf16* __restrict__ qgT, bf16* __restrict__ kgT, bf16* __restrict__ vgp)
{
  __shared__ __align__(16) float xs[64][64];     // [ci][p]
  __shared__ __align__(16) float lows[64][64];
  __shared__ __align__(16) float wbuf[4096];
  __shared__ float bbuf[64];

  int tid = threadIdx.x;
  int blk = blockIdx.x;
  int b = blk / NT, tile = blk % NT;
  int n0 = tile * 64;
  int co = tid & 63, pg = tid >> 6;

  for (int i = 0; i < 16; ++i) {
    int e = i*256 + tid; int c = e >> 6, p = e & 63;
    xs[c][p]   = x[(b*CH + c)*NN + n0 + p];
    lows[c][p] = b2f(lowg[(b*CH + c)*NN + n0 + p]);
  }

  // ---- Q ----
  for (int i = 0; i < 16; ++i) wbuf[i*256+tid] = wsf[OFF_WQ + i*256 + tid];
  if (tid < 64) bbuf[tid] = wsf[OFF_BQ + tid];
  __syncthreads();
  {
    float bq = bbuf[co];
    float4 acc[4];
    #pragma unroll
    for (int q=0;q<4;++q) acc[q] = make_float4(bq,bq,bq,bq);
    for (int ci = 0; ci < 64; ++ci) {
      float wv = wbuf[ci*64 + co];
      const float4* xr = (const float4*)&xs[ci][0];
      #pragma unroll
      for (int q=0;q<4;++q) {
        float4 xv = xr[pg*4+q];
        acc[q].x += wv*xv.x; acc[q].y += wv*xv.y; acc[q].z += wv*xv.z; acc[q].w += wv*xv.w;
      }
    }
    bf16* dq = qgT + ((size_t)(b*NN + n0 + pg*16))*64 + co;
    #pragma unroll
    for (int q=0;q<4;++q) {
      dq[(q*4+0)*64] = f2b(fmaxf(acc[q].x,0.f)); dq[(q*4+1)*64] = f2b(fmaxf(acc[q].y,0.f));
      dq[(q*4+2)*64] = f2b(fmaxf(acc[q].z,0.f)); dq[(q*4+3)*64] = f2b(fmaxf(acc[q].w,0.f));
    }
  }
  // ---- V ----
  __syncthreads();
  for (int i = 0; i < 16; ++i) wbuf[i*256+tid] = wsf[OFF_WV + i*256 + tid];
  if (tid < 64) bbuf[tid] = wsf[OFF_BV + tid];
  __syncthreads();
  {
    float bv = bbuf[co];
    float4 acc[4];
    #pragma unroll
    for (int q=0;q<4;++q) acc[q] = make_float4(bv,bv,bv,bv);
    for (int ci = 0; ci < 64; ++ci) {
      float wv = wbuf[ci*64 + co];
      const float4* xr = (const float4*)&xs[ci][0];
      #pragma unroll
      for (int q=0;q<4;++q) {
        float4 xv = xr[pg*4+q];
        acc[q].x += wv*xv.x; acc[q].y += wv*xv.y; acc[q].z += wv*xv.z; acc[q].w += wv*xv.w;
      }
    }
    bf16* dst = vgp + (b*CH + co)*NN + n0 + pg*16;
    #pragma unroll
    for (int q=0;q<4;++q) {
      dst[q*4+0] = f2b(acc[q].x); dst[q*4+1] = f2b(acc[q].y);
      dst[q*4+2] = f2b(acc[q].z); dst[q*4+3] = f2b(acc[q].w);
    }
  }
  // ---- K (two passes: A1@(x-low), A2@low) ----
  __syncthreads();
  for (int i = 0; i < 16; ++i) wbuf[i*256+tid] = wsf[OFF_A1 + i*256 + tid];
  if (tid < 64) bbuf[tid] = wsf[OFF_BK + tid];
  __syncthreads();
  float4 acck[4];
  {
    float bk = bbuf[co];
    #pragma unroll
    for (int q=0;q<4;++q) acck[q] = make_float4(bk,bk,bk,bk);
    for (int ci = 0; ci < 64; ++ci) {
      float wv = wbuf[ci*64 + co];
      const float4* xr = (const float4*)&xs[ci][0];
      const float4* lr = (const float4*)&lows[ci][0];
      #pragma unroll
      for (int q=0;q<4;++q) {
        float4 xv = xr[pg*4+q], lv = lr[pg*4+q];
        acck[q].x += wv*(xv.x-lv.x); acck[q].y += wv*(xv.y-lv.y);
        acck[q].z += wv*(xv.z-lv.z); acck[q].w += wv*(xv.w-lv.w);
      }
    }
  }
  __syncthreads();
  for (int i = 0; i < 16; ++i) wbuf[i*256+tid] = wsf[OFF_A2 + i*256 + tid];
  __syncthreads();
  {
    for (int ci = 0; ci < 64; ++ci) {
      float wv = wbuf[ci*64 + co];
      const float4* lr = (const float4*)&lows[ci][0];
      #pragma unroll
      for (int q=0;q<4;++q) {
        float4 lv = lr[pg*4+q];
        acck[q].x += wv*lv.x; acck[q].y += wv*lv.y; acck[q].z += wv*lv.z; acck[q].w += wv*lv.w;
      }
    }
    bf16* dk = kgT + ((size_t)(b*NN + n0 + pg*16))*64 + co;
    #pragma unroll
    for (int q=0;q<4;++q) {
      dk[(q*4+0)*64] = f2b(acck[q].x); dk[(q*4+1)*64] = f2b(acck[q].y);
      dk[(q*4+2)*64] = f2b(acck[q].z); dk[(q*4+3)*64] = f2b(acck[q].w);
    }
  }
}

// Split-K MFMA flash attention partial. Block = (b, qtile, split); split handles
// key tiles [split*KTPS, (split+1)*KTPS). Writes unnormalized O' + (m,l).
// A/B frag: lane&15 = row, k = quad*8+j. C/D frag: col=lane&15, row=quad*4+reg.
__global__ __launch_bounds__(256) void attn_partial(
    const bf16* __restrict__ qgT, const bf16* __restrict__ kgT, const bf16* __restrict__ vgp,
    float* __restrict__ part, float* __restrict__ pml)
{
  __shared__ __align__(16) char smem[36864];
  bf16* Qld = (bf16*)smem;              // [64][QP]
  bf16* Kld = (bf16*)(smem + 9216);     // [64][QP]  (m rows)
  bf16* Vld = (bf16*)(smem + 18432);    // [64][QP]  (c rows)
  bf16* Pld = (bf16*)(smem + 27648);    // [64][QP]  (n rows)

  int tid = threadIdx.x;
  int blk = blockIdx.x;
  int b = blk / (NT*KS);
  int rem = blk % (NT*KS);
  int tile = rem / KS, split = rem % KS;
  int n0 = tile*64;
  int wv = tid >> 6, lane = tid & 63, ln = lane & 15, quad = lane >> 4;
  int arow = (wv*16 + ln)*QP;           // this lane's A-frag row base

  // stage Q [n][c]
  #pragma unroll
  for (int i = 0; i < 4; ++i) {
    int f = (i*256 + tid)*4; int n = f >> 6, c = f & 63;
    *(uint2*)&Qld[n*QP + c] = *(const uint2*)&qgT[(size_t)(b*NN + n0 + n)*64 + c];
  }
  __syncthreads();
  short8 aq0 = *(const short8*)&Qld[arow + quad*8];        // hoisted Q frags
  short8 aq1 = *(const short8*)&Qld[arow + 32 + quad*8];

  float m_run[4], l_run[4];
  f4 accO[4];
  #pragma unroll
  for (int r=0;r<4;++r){ m_run[r]=NEGBIG; l_run[r]=0.f; }
  #pragma unroll
  for (int t=0;t<4;++t) accO[t] = (f4){0.f,0.f,0.f,0.f};

  for (int kt = 0; kt < KTPS; ++kt) {
    int m0 = (split*KTPS + kt)*64;
    __syncthreads();   // prior iter's K/V frag reads complete
    #pragma unroll
    for (int i = 0; i < 4; ++i) {
      int f = (i*256 + tid)*4; int rr = f >> 6, cc = f & 63;
      *(uint2*)&Kld[rr*QP + cc] = *(const uint2*)&kgT[(size_t)(b*NN + m0 + rr)*64 + cc];
      *(uint2*)&Vld[rr*QP + cc] = *(const uint2*)&vgp[(size_t)(b*CH + rr)*NN + m0 + cc];
    }
    __syncthreads();

    // ---- S = Q K^T (raw; /8 folded into softmax) ----
    f4 accS[4];
    #pragma unroll
    for (int t = 0; t < 4; ++t) {
      short8 bk0 = *(const short8*)&Kld[(t*16+ln)*QP + quad*8];
      short8 bk1 = *(const short8*)&Kld[(t*16+ln)*QP + 32 + quad*8];
      f4 z = (f4){0.f,0.f,0.f,0.f};
      z = MFMA16(aq0, bk0, z, 0, 0, 0);
      accS[t] = MFMA16(aq1, bk1, z, 0, 0, 0);
    }

    // ---- online softmax (stats per reg r -> row n = wv*16+quad*4+r) ----
    float mnew[4], alpha[4];
    #pragma unroll
    for (int r=0;r<4;++r) {
      float m = fmaxf(fmaxf(accS[0][r],accS[1][r]), fmaxf(accS[2][r],accS[3][r])) * 0.125f;
      m = fmaxf(m, __shfl_xor(m, 1, 16));
      m = fmaxf(m, __shfl_xor(m, 2, 16));
      m = fmaxf(m, __shfl_xor(m, 4, 16));
      m = fmaxf(m, __shfl_xor(m, 8, 16));
      mnew[r]  = fmaxf(m_run[r], m);
      alpha[r] = __expf(m_run[r] - mnew[r]);   // 0 on first tile
      m_run[r] = mnew[r];
    }
    #pragma unroll
    for (int r=0;r<4;++r) {
      int n = wv*16 + quad*4 + r;
      float s = 0.f;
      #pragma unroll
      for (int t=0;t<4;++t) {
        float p = __expf(accS[t][r]*0.125f - mnew[r]);
        Pld[n*QP + t*16 + ln] = f2b(p);
        s += p;
      }
      s += __shfl_xor(s, 1, 16);
      s += __shfl_xor(s, 2, 16);
      s += __shfl_xor(s, 4, 16);
      s += __shfl_xor(s, 8, 16);
      l_run[r] = l_run[r]*alpha[r] + s;
    }

    // ---- O = alpha*O + P V^T (P wave-local: per-wave DS ordering suffices) ----
    f4 al = (f4){alpha[0], alpha[1], alpha[2], alpha[3]};
    #pragma unroll
    for (int t=0;t<4;++t) accO[t] *= al;
    short8 ap0 = *(const short8*)&Pld[arow + quad*8];
    short8 ap1 = *(const short8*)&Pld[arow + 32 + quad*8];
    #pragma unroll
    for (int t = 0; t < 4; ++t) {
      short8 bv0 = *(const short8*)&Vld[(t*16+ln)*QP + quad*8];
      short8 bv1 = *(const short8*)&Vld[(t*16+ln)*QP + 32 + quad*8];
      accO[t] = MFMA16(ap0, bv0, accO[t], 0, 0, 0);
      accO[t] = MFMA16(ap1, bv1, accO[t], 0, 0, 0);
    }
  }

  // ---- store partials ----
  size_t pbase = ((size_t)(b*NT + tile)*KS + split)*4096;
  #pragma unroll
  for (int r=0;r<4;++r) {
    int n = wv*16 + quad*4 + r;
    #pragma unroll
    for (int t=0;t<4;++t)
      part[pbase + n*64 + t*16 + ln] = accO[t][r];
  }
  if (ln == 0) {
    size_t mbase = ((size_t)(b*NT + tile)*KS + split)*128;
    #pragma unroll
    for (int r=0;r<4;++r) {
      int n = wv*16 + quad*4 + r;
      pml[mbase + n]      = m_run[r];
      pml[mbase + 64 + n] = l_run[r];
    }
  }
}

// Merge KS splits + out conv + residual. One block per (b, qtile).
__global__ __launch_bounds__(256) void attn_reduce(
    const float* __restrict__ part, const float* __restrict__ pml,
    const float* __restrict__ x, const float* __restrict__ outw,
    const float* __restrict__ outb, float* __restrict__ out)
{
  __shared__ __align__(16) float Os[64*OP];
  __shared__ __align__(16) float Wot[64*OP];
  __shared__ float alph[KS*64];
  __shared__ float linv[64];

  int tid = threadIdx.x;
  int b = blockIdx.x / NT, tile = blockIdx.x % NT;
  int n0 = tile*64;
  size_t base = (size_t)(b*NT + tile)*KS;

  if (tid < 64) {
    int n = tid;
    float ms[KS], ls[KS];
    #pragma unroll
    for (int s=0;s<KS;++s) {
      ms[s] = pml[(base+s)*128 + n];
      ls[s] = pml[(base+s)*128 + 64 + n];
    }
    float M = ms[0];
    #pragma unroll
    for (int s=1;s<KS;++s) M = fmaxf(M, ms[s]);
    float l = 0.f;
    #pragma unroll
    for (int s=0;s<KS;++s) {
      float a = __expf(ms[s] - M);
      alph[s*64 + n] = a;
      l += a * ls[s];
    }
    linv[n] = 1.0f / l;
  }
  for (int i = 0; i < 16; ++i) {
    int e = i*256 + tid; int co2 = e >> 6, c = e & 63;
    Wot[c*OP + co2] = outw[co2*64 + c];
  }
  __syncthreads();

  for (int i = 0; i < 16; ++i) {
    int e = i*256 + tid; int n = e >> 6, c = e & 63;
    float acc = 0.f;
    #pragma unroll
    for (int s=0;s<KS;++s)
      acc += alph[s*64 + n] * part[(base+s)*4096 + n*64 + c];
    Os[n*OP + c] = acc * linv[n];
  }
  __syncthreads();

  {
    int n = tid & 63, cog = tid >> 6;
    float acc[16];
    #pragma unroll
    for (int k=0;k<16;++k) acc[k] = outb[cog*16+k];
    for (int c = 0; c < 64; ++c) {
      float ov = Os[n*OP + c];
      #pragma unroll
      for (int k=0;k<16;++k) acc[k] += Wot[c*OP + cog*16 + k] * ov;
    }
    #pragma unroll
    for (int k=0;k<16;++k) {
      int co2 = cog*16 + k;
      int idx = (b*CH + co2)*NN + n0 + n;
      out[idx] = acc[k] + x[idx];
    }
  }
}

extern "C" void kernel_launch(void* const* d_in, const int* in_sizes, int n_in,
                              void* d_out, int out_size, void* d_ws, size_t ws_size,
                              hipStream_t stream) {
  const float* x    = (const float*)d_in[0];
  const float* q1w  = (const float*)d_in[1];
  const float* q1g  = (const float*)d_in[2];
  const float* q1b  = (const float*)d_in[3];
  const float* q2w  = (const float*)d_in[4];
  const float* q2g  = (const float*)d_in[5];
  const float* q2b  = (const float*)d_in[6];
  const float* q3w  = (const float*)d_in[7];
  const float* q3g  = (const float*)d_in[8];
  const float* q3b  = (const float*)d_in[9];
  const float* khw  = (const float*)d_in[10];
  const float* khb  = (const float*)d_in[11];
  const float* klw  = (const float*)d_in[12];
  const float* klb  = (const float*)d_in[13];
  const float* kfw  = (const float*)d_in[14];
  const float* kfb  = (const float*)d_in[15];
  const float* vbg  = (const float*)d_in[16];
  const float* vbb  = (const float*)d_in[17];
  const float* vw   = (const float*)d_in[18];
  const float* vb   = (const float*)d_in[19];
  const float* outw = (const float*)d_in[20];
  const float* outb = (const float*)d_in[21];

  float* wsf  = (float*)d_ws;
  char*  wsb  = (char*)d_ws;
  bf16*  lowg = (bf16*)(wsb + OFF_LOW_B);
  bf16*  qgT  = (bf16*)(wsb + OFF_Q_B);
  bf16*  kgT  = (bf16*)(wsb + OFF_K_B);
  bf16*  vgp  = (bf16*)(wsb + OFF_V_B);
  float* part = (float*)(wsb + OFF_P_B);
  float* pml  = (float*)(wsb + OFF_ML_B);

  hipLaunchKernelGGL(setup_fold, dim3(1), dim3(256), 0, stream,
                     q1w,q1g,q1b,q2w,q2g,q2b,q3w,q3g,q3b,
                     khw,khb,klw,klb,kfw,kfb,vbg,vbb,vw,vb, wsf);
  hipLaunchKernelGGL(pool_low, dim3((BATCH*CH*NN)/256), dim3(256), 0, stream, x, lowg);
  hipLaunchKernelGGL(qkv_kernel, dim3(BATCH*NT), dim3(256), 0, stream,
                     x, wsf, lowg, qgT, kgT, vgp);
  hipLaunchKernelGGL(attn_partial, dim3(BATCH*NT*KS), dim3(256), 0, stream,
                     qgT, kgT, vgp, part, pml);
  hipLaunchKernelGGL(attn_reduce, dim3(BATCH*NT), dim3(256), 0, stream,
                     part, pml, x, outw, outb, (float*)d_out);
}

// Round 6
// 284.683 us; speedup vs baseline: 3.0864x; 1.1148x over previous
//
#include <hip/hip_runtime.h>
#include <hip/hip_bf16.h>

// IRChannelAttention on MI355X. Round 6: no-max exp2 flash (register l-sum),
// K/V register prefetch, coalesced V layout, one-pass QKV, fast pool.
// B=2, C=64, H=W=80, N=6400. fp32 global I/O, bf16 ws intermediates.

#define BATCH 2
#define CH 64
#define HH 80
#define WW 80
#define NN 6400
#define NT 100          // NN / 64
#define KS 5            // key splits
#define KTPS (NT/KS)    // 20 key tiles per split
#define EPSV 1e-5f
#define NEGBIG (-1e30f)
#define QP 72           // bf16 LDS tile pitch (16B-aligned rows)
#define LOG2E8 0.18033688f   // log2(e)/8, folded into Q weights

typedef __hip_bfloat16 bf16;
typedef __attribute__((ext_vector_type(8))) short short8;   // MFMA A/B frag
typedef __attribute__((ext_vector_type(4))) float f4;       // MFMA C/D frag
#define MFMA16 __builtin_amdgcn_mfma_f32_16x16x32_bf16

__device__ __forceinline__ float b2f(bf16 v){ return __bfloat162float(v); }
__device__ __forceinline__ bf16 f2b(float v){ return __float2bfloat16(v); }
__device__ __forceinline__ float fexp2(float x){
#if __has_builtin(__builtin_amdgcn_exp2f)
  return __builtin_amdgcn_exp2f(x);
#else
  return exp2f(x);
#endif
}

// ws layout (bytes)
#define OFF_BIAS 0                         // 192 fp32: BQ(64,scaled) BK(64) BV(64)
#define OFF_WH_B 768                       // 4 x 4096 bf16: wq | wv | wa1 | wa2m
#define OFF_LOW_B (768 + 32768)            // lowg bf16 [b][c][n]
#define OFF_Q_B   (OFF_LOW_B + BATCH*CH*NN*2)   // qgT bf16 [b][n][c]
#define OFF_K_B   (OFF_Q_B   + BATCH*CH*NN*2)   // kgT bf16 [b][n][c]
#define OFF_V_B   (OFF_K_B   + BATCH*CH*NN*2)   // vgT bf16 [b][n][c]
#define OFF_P_B   (OFF_V_B   + BATCH*CH*NN*2)   // part fp32 [(b*NT+t)*KS+s][64][64]
#define OFF_ML_B  (OFF_P_B   + BATCH*NT*KS*4096*4) // l fp32 [(b*NT+t)*KS+s][64]
// total ~23.2 MB

__global__ __launch_bounds__(256) void setup_fold(
    const float* __restrict__ q1w, const float* __restrict__ q1g, const float* __restrict__ q1b,
    const float* __restrict__ q2w, const float* __restrict__ q2g, const float* __restrict__ q2b,
    const float* __restrict__ q3w, const float* __restrict__ q3g, const float* __restrict__ q3b,
    const float* __restrict__ khw, const float* __restrict__ khb,
    const float* __restrict__ klw, const float* __restrict__ klb,
    const float* __restrict__ kfw, const float* __restrict__ kfb,
    const float* __restrict__ vg,  const float* __restrict__ vbnb,
    const float* __restrict__ vw,  const float* __restrict__ vb,
    float* __restrict__ biasf, bf16* __restrict__ wh)
{
  int tid = threadIdx.x;
  float rs = rsqrtf(1.0f + EPSV);
  bf16* wq   = wh;
  bf16* wvh  = wh + 4096;
  bf16* wa1  = wh + 8192;
  bf16* wa2m = wh + 12288;
  for (int o = tid; o < 4096; o += 256) {
    int ci = o >> 6, co = o & 63;   // transposed [ci][co]
    float w = 0.f, g;
    if (co < 21)      { g = q1g[co];    if (ci < 21)               w = q1w[co*21 + ci]; }
    else if (co < 42) { g = q2g[co-21]; if (ci >= 21 && ci < 42)   w = q2w[(co-21)*21 + (ci-21)]; }
    else              { g = q3g[co-42]; if (ci >= 42)              w = q3w[(co-42)*22 + (ci-42)]; }
    wq[o] = f2b(w * g * rs * LOG2E8);           // softmax scale folded in
    float a1 = 0.f, a2 = 0.f;
    for (int j = 0; j < 32; ++j) {
      a1 += kfw[co*64 + j]      * khw[j*64 + ci];
      a2 += kfw[co*64 + 32 + j] * klw[j*64 + ci];
    }
    wa1[o]  = f2b(a1);
    wa2m[o] = f2b(a2 - a1);                     // K = A1@x + (A2-A1)@low + bK
    wvh[o]  = f2b(vw[co*64 + ci] * vg[ci] * rs);
  }
  if (tid < 64) {
    int co = tid;
    float bq;
    if (co < 21)      bq = q1b[co];
    else if (co < 42) bq = q2b[co-21];
    else              bq = q3b[co-42];
    biasf[co] = bq * LOG2E8;
    float bk = kfb[co];
    for (int j = 0; j < 32; ++j) {
      bk += kfw[co*64 + j]      * khb[j];
      bk += kfw[co*64 + 32 + j] * klb[j];
    }
    biasf[64 + co] = bk;
    float bv = vb[co];
    for (int ci = 0; ci < 64; ++ci) bv += vw[co*64 + ci] * vbnb[ci];
    biasf[128 + co] = bv;
  }
}

// 4 outputs/thread, aligned float4 sliding windows. grid 800.
__global__ __launch_bounds__(256) void pool_low(const float* __restrict__ x,
                                                bf16* __restrict__ lowg)
{
  int t4 = (blockIdx.x*256 + threadIdx.x)*4;
  int bc = t4 / NN; int n = t4 % NN;
  int h = n / WW, w0 = n % WW;                 // w0 multiple of 4
  const float* p = x + bc*NN;
  float m5[4], m3[4];
  #pragma unroll
  for (int j=0;j<4;++j){ m5[j]=NEGBIG; m3[j]=NEGBIG; }
  #pragma unroll
  for (int dh = -2; dh <= 2; ++dh) {
    int hh = h + dh; if (hh < 0 || hh >= HH) continue;
    float r[12];
    const float* row = p + hh*WW;
    if (w0 >= 4)      { float4 a = *(const float4*)&row[w0-4]; r[0]=a.x;r[1]=a.y;r[2]=a.z;r[3]=a.w; }
    else              { r[0]=NEGBIG;r[1]=NEGBIG;r[2]=NEGBIG;r[3]=NEGBIG; }
    { float4 a = *(const float4*)&row[w0]; r[4]=a.x;r[5]=a.y;r[6]=a.z;r[7]=a.w; }
    if (w0 + 7 < WW)  { float4 a = *(const float4*)&row[w0+4]; r[8]=a.x;r[9]=a.y;r[10]=a.z;r[11]=a.w; }
    else              { r[8]=NEGBIG;r[9]=NEGBIG;r[10]=NEGBIG;r[11]=NEGBIG; }
    bool in3 = (dh >= -1 && dh <= 1);
    #pragma unroll
    for (int j=0;j<4;++j) {
      float v3 = fmaxf(fmaxf(r[3+j], r[4+j]), r[5+j]);
      float v5 = fmaxf(fmaxf(r[2+j], v3), r[6+j]);
      m5[j] = fmaxf(m5[j], v5);
      if (in3) m3[j] = fmaxf(m3[j], v3);
    }
  }
  ushort4 o;
  o.x = ((__hip_bfloat16_raw)f2b(0.5f*(m3[0]+m5[0]))).x;
  o.y = ((__hip_bfloat16_raw)f2b(0.5f*(m3[1]+m5[1]))).x;
  o.z = ((__hip_bfloat16_raw)f2b(0.5f*(m3[2]+m5[2]))).x;
  o.w = ((__hip_bfloat16_raw)f2b(0.5f*(m3[3]+m5[3]))).x;
  *(ushort4*)&lowg[t4] = o;
}

// One block per (b, tile, half): 32 positions. All weights LDS-resident (bf16),
// single barrier, one pass each for Q, V, K. Q/K/V all stored [b][n][c] coalesced.
__global__ __launch_bounds__(256) void qkv_kernel(
    const float* __restrict__ x, const float* __restrict__ biasf,
    const bf16* __restrict__ wh, const bf16* __restrict__ lowg,
    bf16* __restrict__ qgT, bf16* __restrict__ kgT, bf16* __restrict__ vgT)
{
  __shared__ __align__(16) float xs[64*32];
  __shared__ __align__(16) float lows[64*32];
  __shared__ __align__(16) bf16  wbuf[16384];   // wq | wv | wa1 | wa2m
  __shared__ float bias[192];

  int tid = threadIdx.x;
  int blk = blockIdx.x;
  int b = blk / (NT*2);
  int rem = blk % (NT*2);
  int tile = rem >> 1, half = rem & 1;
  int n0 = tile*64 + half*32;

  #pragma unroll
  for (int i = 0; i < 8; ++i) {
    int e = i*256 + tid; int c = e >> 5, p = e & 31;
    xs[c*32 + p]   = x[(b*CH + c)*NN + n0 + p];
    lows[c*32 + p] = b2f(lowg[(b*CH + c)*NN + n0 + p]);
  }
  #pragma unroll
  for (int i = 0; i < 16; ++i)
    ((uint2*)wbuf)[i*256 + tid] = ((const uint2*)wh)[i*256 + tid];
  if (tid < 192) bias[tid] = biasf[tid];
  __syncthreads();

  int co = tid & 63, pg = tid >> 6;   // 8 positions per thread
  const bf16* wq   = wbuf;
  const bf16* wvh  = wbuf + 4096;
  const bf16* wa1  = wbuf + 8192;
  const bf16* wa2m = wbuf + 12288;

  // ---- Q (scaled, ReLU) ----
  {
    float bq = bias[co];
    float4 a0 = make_float4(bq,bq,bq,bq), a1v = a0;
    for (int ci = 0; ci < 64; ++ci) {
      float wv = b2f(wq[ci*64 + co]);
      float4 x0 = *(const float4*)&xs[ci*32 + pg*8];
      float4 x1 = *(const float4*)&xs[ci*32 + pg*8 + 4];
      a0.x += wv*x0.x; a0.y += wv*x0.y; a0.z += wv*x0.z; a0.w += wv*x0.w;
      a1v.x += wv*x1.x; a1v.y += wv*x1.y; a1v.z += wv*x1.z; a1v.w += wv*x1.w;
    }
    float q8[8] = {a0.x,a0.y,a0.z,a0.w,a1v.x,a1v.y,a1v.z,a1v.w};
    #pragma unroll
    for (int j=0;j<8;++j)
      qgT[(size_t)(b*NN + n0 + pg*8 + j)*64 + co] = f2b(fmaxf(q8[j], 0.f));
  }
  // ---- V ----
  {
    float bv = bias[128 + co];
    float4 a0 = make_float4(bv,bv,bv,bv), a1v = a0;
    for (int ci = 0; ci < 64; ++ci) {
      float wv = b2f(wvh[ci*64 + co]);
      float4 x0 = *(const float4*)&xs[ci*32 + pg*8];
      float4 x1 = *(const float4*)&xs[ci*32 + pg*8 + 4];
      a0.x += wv*x0.x; a0.y += wv*x0.y; a0.z += wv*x0.z; a0.w += wv*x0.w;
      a1v.x += wv*x1.x; a1v.y += wv*x1.y; a1v.z += wv*x1.z; a1v.w += wv*x1.w;
    }
    float v8[8] = {a0.x,a0.y,a0.z,a0.w,a1v.x,a1v.y,a1v.z,a1v.w};
    #pragma unroll
    for (int j=0;j<8;++j)
      vgT[(size_t)(b*NN + n0 + pg*8 + j)*64 + co] = f2b(v8[j]);
  }
  // ---- K = A1@x + (A2-A1)@low + bK (one pass) ----
  {
    float bk = bias[64 + co];
    float4 a0 = make_float4(bk,bk,bk,bk), a1v = a0;
    for (int ci = 0; ci < 64; ++ci) {
      float w1 = b2f(wa1[ci*64 + co]);
      float w2 = b2f(wa2m[ci*64 + co]);
      float4 x0 = *(const float4*)&xs[ci*32 + pg*8];
      float4 x1 = *(const float4*)&xs[ci*32 + pg*8 + 4];
      float4 l0 = *(const float4*)&lows[ci*32 + pg*8];
      float4 l1 = *(const float4*)&lows[ci*32 + pg*8 + 4];
      a0.x += w1*x0.x + w2*l0.x; a0.y += w1*x0.y + w2*l0.y;
      a0.z += w1*x0.z + w2*l0.z; a0.w += w1*x0.w + w2*l0.w;
      a1v.x += w1*x1.x + w2*l1.x; a1v.y += w1*x1.y + w2*l1.y;
      a1v.z += w1*x1.z + w2*l1.z; a1v.w += w1*x1.w + w2*l1.w;
    }
    float k8[8] = {a0.x,a0.y,a0.z,a0.w,a1v.x,a1v.y,a1v.z,a1v.w};
    #pragma unroll
    for (int j=0;j<8;++j)
      kgT[(size_t)(b*NN + n0 + pg*8 + j)*64 + co] = f2b(k8[j]);
  }
}

// Split-K MFMA flash, no max-stabilizer (P = exp2(S_scaled), bounded by data),
// register l accumulation, register prefetch of next K/V tile.
__global__ __launch_bounds__(256) void attn_partial(
    const bf16* __restrict__ qgT, const bf16* __restrict__ kgT, const bf16* __restrict__ vgT,
    float* __restrict__ part, float* __restrict__ pml)
{
  __shared__ __align__(16) char smem[36864];
  bf16* Qld = (bf16*)smem;              // [64][QP] n rows
  bf16* Kld = (bf16*)(smem + 9216);     // [64][QP] m rows
  bf16* Vld = (bf16*)(smem + 18432);    // [64][QP] c rows
  bf16* Pld = (bf16*)(smem + 27648);    // [64][QP] n rows

  int tid = threadIdx.x;
  int blk = blockIdx.x;
  int b = blk / (NT*KS);
  int rem = blk % (NT*KS);
  int tile = rem / KS, split = rem % KS;
  int n0 = tile*64;
  int wv = tid >> 6, lane = tid & 63, ln = lane & 15, quad = lane >> 4;
  int arow = (wv*16 + ln)*QP;

  // stage Q [n][c]
  #pragma unroll
  for (int i = 0; i < 4; ++i) {
    int f = (i*256 + tid)*4; int n = f >> 6, c = f & 63;
    *(uint2*)&Qld[n*QP + c] = *(const uint2*)&qgT[(size_t)(b*NN + n0 + n)*64 + c];
  }
  __syncthreads();
  short8 aq0 = *(const short8*)&Qld[arow + quad*8];
  short8 aq1 = *(const short8*)&Qld[arow + 32 + quad*8];

  f4 accO[4];
  float lacc[4];
  #pragma unroll
  for (int t=0;t<4;++t) accO[t] = (f4){0.f,0.f,0.f,0.f};
  #pragma unroll
  for (int r=0;r<4;++r) lacc[r] = 0.f;

  // prefetch tile 0
  uint2 kreg[4], vreg[4];
  int mbase = split*KTPS*64;
  #pragma unroll
  for (int i = 0; i < 4; ++i) {
    int f = (i*256 + tid)*4; int rr = f >> 6, cc = f & 63;
    kreg[i] = *(const uint2*)&kgT[(size_t)(b*NN + mbase + rr)*64 + cc];
    vreg[i] = *(const uint2*)&vgT[(size_t)(b*NN + mbase + rr)*64 + cc];
  }

  for (int kt = 0; kt < KTPS; ++kt) {
    __syncthreads();   // prev iter frag reads done
    #pragma unroll
    for (int i = 0; i < 4; ++i) {
      int f = (i*256 + tid)*4; int rr = f >> 6, cc = f & 63;
      *(uint2*)&Kld[rr*QP + cc] = kreg[i];
      bf16* pv = (bf16*)&vreg[i];
      #pragma unroll
      for (int j=0;j<4;++j) Vld[(cc+j)*QP + rr] = pv[j];   // transpose to [c][m]
    }
    __syncthreads();
    if (kt + 1 < KTPS) {
      int m0 = mbase + (kt+1)*64;
      #pragma unroll
      for (int i = 0; i < 4; ++i) {
        int f = (i*256 + tid)*4; int rr = f >> 6, cc = f & 63;
        kreg[i] = *(const uint2*)&kgT[(size_t)(b*NN + m0 + rr)*64 + cc];
        vreg[i] = *(const uint2*)&vgT[(size_t)(b*NN + m0 + rr)*64 + cc];
      }
    }

    // ---- S = Q_scaled K^T ----
    f4 accS[4];
    #pragma unroll
    for (int t = 0; t < 4; ++t) {
      short8 bk0 = *(const short8*)&Kld[(t*16+ln)*QP + quad*8];
      short8 bk1 = *(const short8*)&Kld[(t*16+ln)*QP + 32 + quad*8];
      f4 z = (f4){0.f,0.f,0.f,0.f};
      z = MFMA16(aq0, bk0, z, 0, 0, 0);
      accS[t] = MFMA16(aq1, bk1, z, 0, 0, 0);
    }

    // ---- P = exp2(S); l accumulates in registers (no cross-lane ops) ----
    #pragma unroll
    for (int r=0;r<4;++r) {
      int n = wv*16 + quad*4 + r;
      #pragma unroll
      for (int t=0;t<4;++t) {
        float p = fexp2(accS[t][r]);
        Pld[n*QP + t*16 + ln] = f2b(p);
        lacc[r] += p;
      }
    }

    // ---- O += P V^T (P wave-local; per-wave DS ordering suffices) ----
    short8 ap0 = *(const short8*)&Pld[arow + quad*8];
    short8 ap1 = *(const short8*)&Pld[arow + 32 + quad*8];
    #pragma unroll
    for (int t = 0; t < 4; ++t) {
      short8 bv0 = *(const short8*)&Vld[(t*16+ln)*QP + quad*8];
      short8 bv1 = *(const short8*)&Vld[(t*16+ln)*QP + 32 + quad*8];
      accO[t] = MFMA16(ap0, bv0, accO[t], 0, 0, 0);
      accO[t] = MFMA16(ap1, bv1, accO[t], 0, 0, 0);
    }
  }

  // ---- store partials; one butterfly per block for l ----
  size_t pbase = ((size_t)(b*NT + tile)*KS + split)*4096;
  #pragma unroll
  for (int r=0;r<4;++r) {
    int n = wv*16 + quad*4 + r;
    #pragma unroll
    for (int t=0;t<4;++t)
      part[pbase + n*64 + t*16 + ln] = accO[t][r];
  }
  size_t mlb = ((size_t)(b*NT + tile)*KS + split)*64;
  #pragma unroll
  for (int r=0;r<4;++r) {
    float s = lacc[r];
    s += __shfl_xor(s, 1, 16);
    s += __shfl_xor(s, 2, 16);
    s += __shfl_xor(s, 4, 16);
    s += __shfl_xor(s, 8, 16);
    if (ln == 0) pml[mlb + wv*16 + quad*4 + r] = s;
  }
}

// Merge KS splits + out conv + residual. One block per (b, tile, half=32 rows).
__global__ __launch_bounds__(256) void attn_reduce(
    const float* __restrict__ part, const float* __restrict__ pml,
    const float* __restrict__ x, const float* __restrict__ outw,
    const float* __restrict__ outb, float* __restrict__ out)
{
  __shared__ __align__(16) float Os[32*65];
  __shared__ __align__(16) float Wot[64*65];
  __shared__ float linv[32];

  int tid = threadIdx.x;
  int blk = blockIdx.x;
  int b = blk / (NT*2);
  int rem = blk % (NT*2);
  int tile = rem >> 1, half = rem & 1;
  int nb = half*32;
  size_t base = (size_t)(b*NT + tile)*KS;

  for (int i = 0; i < 16; ++i) {
    int e = i*256 + tid; int co2 = e >> 6, c = e & 63;
    Wot[c*65 + co2] = outw[co2*64 + c];
  }
  if (tid < 32) {
    float l = 0.f;
    #pragma unroll
    for (int s=0;s<KS;++s) l += pml[(base+s)*64 + nb + tid];
    linv[tid] = 1.0f / l;
  }
  __syncthreads();

  #pragma unroll
  for (int i = 0; i < 8; ++i) {
    int e = i*256 + tid; int n = e >> 6, c = e & 63;
    float a = 0.f;
    #pragma unroll
    for (int s=0;s<KS;++s)
      a += part[(base+s)*4096 + (size_t)(nb+n)*64 + c];
    Os[n*65 + c] = a * linv[n];
  }
  __syncthreads();

  {
    int n = tid & 31, cog = tid >> 5;   // 8 groups x 8 channels
    float acc[8];
    #pragma unroll
    for (int k=0;k<8;++k) acc[k] = outb[cog*8 + k];
    for (int c = 0; c < 64; ++c) {
      float ov = Os[n*65 + c];
      #pragma unroll
      for (int k=0;k<8;++k) acc[k] += Wot[c*65 + cog*8 + k] * ov;
    }
    #pragma unroll
    for (int k=0;k<8;++k) {
      int co2 = cog*8 + k;
      int idx = (b*CH + co2)*NN + tile*64 + nb + n;
      out[idx] = acc[k] + x[idx];
    }
  }
}

extern "C" void kernel_launch(void* const* d_in, const int* in_sizes, int n_in,
                              void* d_out, int out_size, void* d_ws, size_t ws_size,
                              hipStream_t stream) {
  const float* x    = (const float*)d_in[0];
  const float* q1w  = (const float*)d_in[1];
  const float* q1g  = (const float*)d_in[2];
  const float* q1b  = (const float*)d_in[3];
  const float* q2w  = (const float*)d_in[4];
  const float* q2g  = (const float*)d_in[5];
  const float* q2b  = (const float*)d_in[6];
  const float* q3w  = (const float*)d_in[7];
  const float* q3g  = (const float*)d_in[8];
  const float* q3b  = (const float*)d_in[9];
  const float* khw  = (const float*)d_in[10];
  const float* khb  = (const float*)d_in[11];
  const float* klw  = (const float*)d_in[12];
  const float* klb  = (const float*)d_in[13];
  const float* kfw  = (const float*)d_in[14];
  const float* kfb  = (const float*)d_in[15];
  const float* vbg  = (const float*)d_in[16];
  const float* vbb  = (const float*)d_in[17];
  const float* vw   = (const float*)d_in[18];
  const float* vb   = (const float*)d_in[19];
  const float* outw = (const float*)d_in[20];
  const float* outb = (const float*)d_in[21];

  char*  wsb  = (char*)d_ws;
  float* biasf= (float*)(wsb + OFF_BIAS);
  bf16*  wh   = (bf16*)(wsb + OFF_WH_B);
  bf16*  lowg = (bf16*)(wsb + OFF_LOW_B);
  bf16*  qgT  = (bf16*)(wsb + OFF_Q_B);
  bf16*  kgT  = (bf16*)(wsb + OFF_K_B);
  bf16*  vgT  = (bf16*)(wsb + OFF_V_B);
  float* part = (float*)(wsb + OFF_P_B);
  float* pml  = (float*)(wsb + OFF_ML_B);

  hipLaunchKernelGGL(setup_fold, dim3(1), dim3(256), 0, stream,
                     q1w,q1g,q1b,q2w,q2g,q2b,q3w,q3g,q3b,
                     khw,khb,klw,klb,kfw,kfb,vbg,vbb,vw,vb, biasf, wh);
  hipLaunchKernelGGL(pool_low, dim3(BATCH*CH*NN/1024), dim3(256), 0, stream, x, lowg);
  hipLaunchKernelGGL(qkv_kernel, dim3(BATCH*NT*2), dim3(256), 0, stream,
                     x, biasf, wh, lowg, qgT, kgT, vgT);
  hipLaunchKernelGGL(attn_partial, dim3(BATCH*NT*KS), dim3(256), 0, stream,
                     qgT, kgT, vgT, part, pml);
  hipLaunchKernelGGL(attn_reduce, dim3(BATCH*NT*2), dim3(256), 0, stream,
                     part, pml, x, outw, outb, (float*)d_out);
}

// Round 7
// 205.915 us; speedup vs baseline: 4.2670x; 1.3825x over previous
//
#include <hip/hip_runtime.h>
#include <hip/hip_bf16.h>

// IRChannelAttention on MI355X. Round 7: parallel LDS-staged setup_fold
// (was single-block, 90us latency-bound). Rest identical to round 6.
// B=2, C=64, H=W=80, N=6400. fp32 global I/O, bf16 ws intermediates.

#define BATCH 2
#define CH 64
#define HH 80
#define WW 80
#define NN 6400
#define NT 100          // NN / 64
#define KS 5            // key splits
#define KTPS (NT/KS)    // 20 key tiles per split
#define EPSV 1e-5f
#define NEGBIG (-1e30f)
#define QP 72           // bf16 LDS tile pitch (16B-aligned rows)
#define LOG2E8 0.18033688f   // log2(e)/8, folded into Q weights

typedef __hip_bfloat16 bf16;
typedef __attribute__((ext_vector_type(8))) short short8;   // MFMA A/B frag
typedef __attribute__((ext_vector_type(4))) float f4;       // MFMA C/D frag
#define MFMA16 __builtin_amdgcn_mfma_f32_16x16x32_bf16

__device__ __forceinline__ float b2f(bf16 v){ return __bfloat162float(v); }
__device__ __forceinline__ bf16 f2b(float v){ return __float2bfloat16(v); }
__device__ __forceinline__ float fexp2(float x){
#if __has_builtin(__builtin_amdgcn_exp2f)
  return __builtin_amdgcn_exp2f(x);
#else
  return exp2f(x);
#endif
}

// ws layout (bytes)
#define OFF_BIAS 0                         // 192 fp32: BQ(64,scaled) BK(64) BV(64)
#define OFF_WH_B 768                       // 4 x 4096 bf16: wq | wv | wa1 | wa2m
#define OFF_LOW_B (768 + 32768)            // lowg bf16 [b][c][n]
#define OFF_Q_B   (OFF_LOW_B + BATCH*CH*NN*2)   // qgT bf16 [b][n][c]
#define OFF_K_B   (OFF_Q_B   + BATCH*CH*NN*2)   // kgT bf16 [b][n][c]
#define OFF_V_B   (OFF_K_B   + BATCH*CH*NN*2)   // vgT bf16 [b][n][c]
#define OFF_P_B   (OFF_V_B   + BATCH*CH*NN*2)   // part fp32 [(b*NT+t)*KS+s][64][64]
#define OFF_ML_B  (OFF_P_B   + BATCH*NT*KS*4096*4) // l fp32 [(b*NT+t)*KS+s][64]
// total ~23.2 MB

// grid 16 x 256: one (ci,co) per thread; lane -> ci (stride-1 LDS reads),
// co wave-uniform (broadcast LDS reads). Weights staged to LDS once per block.
__global__ __launch_bounds__(256) void setup_fold(
    const float* __restrict__ q1w, const float* __restrict__ q1g, const float* __restrict__ q1b,
    const float* __restrict__ q2w, const float* __restrict__ q2g, const float* __restrict__ q2b,
    const float* __restrict__ q3w, const float* __restrict__ q3g, const float* __restrict__ q3b,
    const float* __restrict__ khw, const float* __restrict__ khb,
    const float* __restrict__ klw, const float* __restrict__ klb,
    const float* __restrict__ kfw, const float* __restrict__ kfb,
    const float* __restrict__ vg,  const float* __restrict__ vbnb,
    const float* __restrict__ vw,  const float* __restrict__ vb,
    float* __restrict__ biasf, bf16* __restrict__ wh)
{
  __shared__ __align__(16) float skf[4096];   // kfw [co][64]
  __shared__ __align__(16) float skh[2048];   // khw [j][64ci]
  __shared__ __align__(16) float skl[2048];   // klw [j][64ci]

  int tid = threadIdx.x;
  int blk = blockIdx.x;
  #pragma unroll
  for (int i = 0; i < 4; ++i)
    *(float4*)&skf[(i*256 + tid)*4] = *(const float4*)&kfw[(i*256 + tid)*4];
  #pragma unroll
  for (int i = 0; i < 2; ++i) {
    *(float4*)&skh[(i*256 + tid)*4] = *(const float4*)&khw[(i*256 + tid)*4];
    *(float4*)&skl[(i*256 + tid)*4] = *(const float4*)&klw[(i*256 + tid)*4];
  }
  __syncthreads();

  float rs = rsqrtf(1.0f + EPSV);
  bf16* wq   = wh;
  bf16* wvh  = wh + 4096;
  bf16* wa1  = wh + 8192;
  bf16* wa2m = wh + 12288;

  int t = blk*256 + tid;
  int ci = t & 63, co = t >> 6;        // co uniform per wave-half; ci = lane-fast
  int o = ci*64 + co;                  // transposed [ci][co] storage index

  // Q: block-diagonal grouped conv, BN scale + softmax scale folded
  float w = 0.f, g;
  if (co < 21)      { g = q1g[co];    w = (ci < 21)              ? q1w[co*21 + ci]            : 0.f; }
  else if (co < 42) { g = q2g[co-21]; w = (ci >= 21 && ci < 42)  ? q2w[(co-21)*21 + (ci-21)]  : 0.f; }
  else              { g = q3g[co-42]; w = (ci >= 42)             ? q3w[(co-42)*22 + (ci-42)]  : 0.f; }
  wq[o] = f2b(w * g * rs * LOG2E8);

  // K composite from LDS: skf broadcast (co uniform), skh/skl stride-1 (ci=lane)
  float a1 = 0.f, a2 = 0.f;
  #pragma unroll
  for (int j = 0; j < 32; ++j) {
    a1 += skf[co*64 + j]      * skh[j*64 + ci];
    a2 += skf[co*64 + 32 + j] * skl[j*64 + ci];
  }
  wa1[o]  = f2b(a1);
  wa2m[o] = f2b(a2 - a1);              // K = A1@x + (A2-A1)@low + bK
  wvh[o]  = f2b(vw[co*64 + ci] * vg[ci] * rs);

  if (blk == 0 && tid < 64) {
    int c2 = tid;
    float bq;
    if (c2 < 21)      bq = q1b[c2];
    else if (c2 < 42) bq = q2b[c2-21];
    else              bq = q3b[c2-42];
    biasf[c2] = bq * LOG2E8;
    float bk = kfb[c2];
    #pragma unroll
    for (int j = 0; j < 32; ++j) {
      bk += skf[c2*64 + j]      * khb[j];
      bk += skf[c2*64 + 32 + j] * klb[j];
    }
    biasf[64 + c2] = bk;
    float bv = vb[c2];
    for (int ci2 = 0; ci2 < 64; ++ci2) bv += vw[c2*64 + ci2] * vbnb[ci2];
    biasf[128 + c2] = bv;
  }
}

// 4 outputs/thread, aligned float4 sliding windows. grid 800.
__global__ __launch_bounds__(256) void pool_low(const float* __restrict__ x,
                                                bf16* __restrict__ lowg)
{
  int t4 = (blockIdx.x*256 + threadIdx.x)*4;
  int bc = t4 / NN; int n = t4 % NN;
  int h = n / WW, w0 = n % WW;                 // w0 multiple of 4
  const float* p = x + bc*NN;
  float m5[4], m3[4];
  #pragma unroll
  for (int j=0;j<4;++j){ m5[j]=NEGBIG; m3[j]=NEGBIG; }
  #pragma unroll
  for (int dh = -2; dh <= 2; ++dh) {
    int hh = h + dh; if (hh < 0 || hh >= HH) continue;
    float r[12];
    const float* row = p + hh*WW;
    if (w0 >= 4)      { float4 a = *(const float4*)&row[w0-4]; r[0]=a.x;r[1]=a.y;r[2]=a.z;r[3]=a.w; }
    else              { r[0]=NEGBIG;r[1]=NEGBIG;r[2]=NEGBIG;r[3]=NEGBIG; }
    { float4 a = *(const float4*)&row[w0]; r[4]=a.x;r[5]=a.y;r[6]=a.z;r[7]=a.w; }
    if (w0 + 7 < WW)  { float4 a = *(const float4*)&row[w0+4]; r[8]=a.x;r[9]=a.y;r[10]=a.z;r[11]=a.w; }
    else              { r[8]=NEGBIG;r[9]=NEGBIG;r[10]=NEGBIG;r[11]=NEGBIG; }
    bool in3 = (dh >= -1 && dh <= 1);
    #pragma unroll
    for (int j=0;j<4;++j) {
      float v3 = fmaxf(fmaxf(r[3+j], r[4+j]), r[5+j]);
      float v5 = fmaxf(fmaxf(r[2+j], v3), r[6+j]);
      m5[j] = fmaxf(m5[j], v5);
      if (in3) m3[j] = fmaxf(m3[j], v3);
    }
  }
  ushort4 o;
  o.x = ((__hip_bfloat16_raw)f2b(0.5f*(m3[0]+m5[0]))).x;
  o.y = ((__hip_bfloat16_raw)f2b(0.5f*(m3[1]+m5[1]))).x;
  o.z = ((__hip_bfloat16_raw)f2b(0.5f*(m3[2]+m5[2]))).x;
  o.w = ((__hip_bfloat16_raw)f2b(0.5f*(m3[3]+m5[3]))).x;
  *(ushort4*)&lowg[t4] = o;
}

// One block per (b, tile, half): 32 positions. All weights LDS-resident (bf16),
// single barrier, one pass each for Q, V, K. Q/K/V all stored [b][n][c] coalesced.
__global__ __launch_bounds__(256) void qkv_kernel(
    const float* __restrict__ x, const float* __restrict__ biasf,
    const bf16* __restrict__ wh, const bf16* __restrict__ lowg,
    bf16* __restrict__ qgT, bf16* __restrict__ kgT, bf16* __restrict__ vgT)
{
  __shared__ __align__(16) float xs[64*32];
  __shared__ __align__(16) float lows[64*32];
  __shared__ __align__(16) bf16  wbuf[16384];   // wq | wv | wa1 | wa2m
  __shared__ float bias[192];

  int tid = threadIdx.x;
  int blk = blockIdx.x;
  int b = blk / (NT*2);
  int rem = blk % (NT*2);
  int tile = rem >> 1, half = rem & 1;
  int n0 = tile*64 + half*32;

  #pragma unroll
  for (int i = 0; i < 8; ++i) {
    int e = i*256 + tid; int c = e >> 5, p = e & 31;
    xs[c*32 + p]   = x[(b*CH + c)*NN + n0 + p];
    lows[c*32 + p] = b2f(lowg[(b*CH + c)*NN + n0 + p]);
  }
  #pragma unroll
  for (int i = 0; i < 16; ++i)
    ((uint2*)wbuf)[i*256 + tid] = ((const uint2*)wh)[i*256 + tid];
  if (tid < 192) bias[tid] = biasf[tid];
  __syncthreads();

  int co = tid & 63, pg = tid >> 6;   // 8 positions per thread
  const bf16* wq   = wbuf;
  const bf16* wvh  = wbuf + 4096;
  const bf16* wa1  = wbuf + 8192;
  const bf16* wa2m = wbuf + 12288;

  // ---- Q (scaled, ReLU) ----
  {
    float bq = bias[co];
    float4 a0 = make_float4(bq,bq,bq,bq), a1v = a0;
    for (int ci = 0; ci < 64; ++ci) {
      float wv = b2f(wq[ci*64 + co]);
      float4 x0 = *(const float4*)&xs[ci*32 + pg*8];
      float4 x1 = *(const float4*)&xs[ci*32 + pg*8 + 4];
      a0.x += wv*x0.x; a0.y += wv*x0.y; a0.z += wv*x0.z; a0.w += wv*x0.w;
      a1v.x += wv*x1.x; a1v.y += wv*x1.y; a1v.z += wv*x1.z; a1v.w += wv*x1.w;
    }
    float q8[8] = {a0.x,a0.y,a0.z,a0.w,a1v.x,a1v.y,a1v.z,a1v.w};
    #pragma unroll
    for (int j=0;j<8;++j)
      qgT[(size_t)(b*NN + n0 + pg*8 + j)*64 + co] = f2b(fmaxf(q8[j], 0.f));
  }
  // ---- V ----
  {
    float bv = bias[128 + co];
    float4 a0 = make_float4(bv,bv,bv,bv), a1v = a0;
    for (int ci = 0; ci < 64; ++ci) {
      float wv = b2f(wvh[ci*64 + co]);
      float4 x0 = *(const float4*)&xs[ci*32 + pg*8];
      float4 x1 = *(const float4*)&xs[ci*32 + pg*8 + 4];
      a0.x += wv*x0.x; a0.y += wv*x0.y; a0.z += wv*x0.z; a0.w += wv*x0.w;
      a1v.x += wv*x1.x; a1v.y += wv*x1.y; a1v.z += wv*x1.z; a1v.w += wv*x1.w;
    }
    float v8[8] = {a0.x,a0.y,a0.z,a0.w,a1v.x,a1v.y,a1v.z,a1v.w};
    #pragma unroll
    for (int j=0;j<8;++j)
      vgT[(size_t)(b*NN + n0 + pg*8 + j)*64 + co] = f2b(v8[j]);
  }
  // ---- K = A1@x + (A2-A1)@low + bK (one pass) ----
  {
    float bk = bias[64 + co];
    float4 a0 = make_float4(bk,bk,bk,bk), a1v = a0;
    for (int ci = 0; ci < 64; ++ci) {
      float w1 = b2f(wa1[ci*64 + co]);
      float w2 = b2f(wa2m[ci*64 + co]);
      float4 x0 = *(const float4*)&xs[ci*32 + pg*8];
      float4 x1 = *(const float4*)&xs[ci*32 + pg*8 + 4];
      float4 l0 = *(const float4*)&lows[ci*32 + pg*8];
      float4 l1 = *(const float4*)&lows[ci*32 + pg*8 + 4];
      a0.x += w1*x0.x + w2*l0.x; a0.y += w1*x0.y + w2*l0.y;
      a0.z += w1*x0.z + w2*l0.z; a0.w += w1*x0.w + w2*l0.w;
      a1v.x += w1*x1.x + w2*l1.x; a1v.y += w1*x1.y + w2*l1.y;
      a1v.z += w1*x1.z + w2*l1.z; a1v.w += w1*x1.w + w2*l1.w;
    }
    float k8[8] = {a0.x,a0.y,a0.z,a0.w,a1v.x,a1v.y,a1v.z,a1v.w};
    #pragma unroll
    for (int j=0;j<8;++j)
      kgT[(size_t)(b*NN + n0 + pg*8 + j)*64 + co] = f2b(k8[j]);
  }
}

// Split-K MFMA flash, no max-stabilizer (P = exp2(S_scaled), bounded by data),
// register l accumulation, register prefetch of next K/V tile.
__global__ __launch_bounds__(256) void attn_partial(
    const bf16* __restrict__ qgT, const bf16* __restrict__ kgT, const bf16* __restrict__ vgT,
    float* __restrict__ part, float* __restrict__ pml)
{
  __shared__ __align__(16) char smem[36864];
  bf16* Qld = (bf16*)smem;              // [64][QP] n rows
  bf16* Kld = (bf16*)(smem + 9216);     // [64][QP] m rows
  bf16* Vld = (bf16*)(smem + 18432);    // [64][QP] c rows
  bf16* Pld = (bf16*)(smem + 27648);    // [64][QP] n rows

  int tid = threadIdx.x;
  int blk = blockIdx.x;
  int b = blk / (NT*KS);
  int rem = blk % (NT*KS);
  int tile = rem / KS, split = rem % KS;
  int n0 = tile*64;
  int wv = tid >> 6, lane = tid & 63, ln = lane & 15, quad = lane >> 4;
  int arow = (wv*16 + ln)*QP;

  // stage Q [n][c]
  #pragma unroll
  for (int i = 0; i < 4; ++i) {
    int f = (i*256 + tid)*4; int n = f >> 6, c = f & 63;
    *(uint2*)&Qld[n*QP + c] = *(const uint2*)&qgT[(size_t)(b*NN + n0 + n)*64 + c];
  }
  __syncthreads();
  short8 aq0 = *(const short8*)&Qld[arow + quad*8];
  short8 aq1 = *(const short8*)&Qld[arow + 32 + quad*8];

  f4 accO[4];
  float lacc[4];
  #pragma unroll
  for (int t=0;t<4;++t) accO[t] = (f4){0.f,0.f,0.f,0.f};
  #pragma unroll
  for (int r=0;r<4;++r) lacc[r] = 0.f;

  // prefetch tile 0
  uint2 kreg[4], vreg[4];
  int mbase = split*KTPS*64;
  #pragma unroll
  for (int i = 0; i < 4; ++i) {
    int f = (i*256 + tid)*4; int rr = f >> 6, cc = f & 63;
    kreg[i] = *(const uint2*)&kgT[(size_t)(b*NN + mbase + rr)*64 + cc];
    vreg[i] = *(const uint2*)&vgT[(size_t)(b*NN + mbase + rr)*64 + cc];
  }

  for (int kt = 0; kt < KTPS; ++kt) {
    __syncthreads();   // prev iter frag reads done
    #pragma unroll
    for (int i = 0; i < 4; ++i) {
      int f = (i*256 + tid)*4; int rr = f >> 6, cc = f & 63;
      *(uint2*)&Kld[rr*QP + cc] = kreg[i];
      bf16* pv = (bf16*)&vreg[i];
      #pragma unroll
      for (int j=0;j<4;++j) Vld[(cc+j)*QP + rr] = pv[j];   // transpose to [c][m]
    }
    __syncthreads();
    if (kt + 1 < KTPS) {
      int m0 = mbase + (kt+1)*64;
      #pragma unroll
      for (int i = 0; i < 4; ++i) {
        int f = (i*256 + tid)*4; int rr = f >> 6, cc = f & 63;
        kreg[i] = *(const uint2*)&kgT[(size_t)(b*NN + m0 + rr)*64 + cc];
        vreg[i] = *(const uint2*)&vgT[(size_t)(b*NN + m0 + rr)*64 + cc];
      }
    }

    // ---- S = Q_scaled K^T ----
    f4 accS[4];
    #pragma unroll
    for (int t = 0; t < 4; ++t) {
      short8 bk0 = *(const short8*)&Kld[(t*16+ln)*QP + quad*8];
      short8 bk1 = *(const short8*)&Kld[(t*16+ln)*QP + 32 + quad*8];
      f4 z = (f4){0.f,0.f,0.f,0.f};
      z = MFMA16(aq0, bk0, z, 0, 0, 0);
      accS[t] = MFMA16(aq1, bk1, z, 0, 0, 0);
    }

    // ---- P = exp2(S); l accumulates in registers (no cross-lane ops) ----
    #pragma unroll
    for (int r=0;r<4;++r) {
      int n = wv*16 + quad*4 + r;
      #pragma unroll
      for (int t=0;t<4;++t) {
        float p = fexp2(accS[t][r]);
        Pld[n*QP + t*16 + ln] = f2b(p);
        lacc[r] += p;
      }
    }

    // ---- O += P V^T (P wave-local; per-wave DS ordering suffices) ----
    short8 ap0 = *(const short8*)&Pld[arow + quad*8];
    short8 ap1 = *(const short8*)&Pld[arow + 32 + quad*8];
    #pragma unroll
    for (int t = 0; t < 4; ++t) {
      short8 bv0 = *(const short8*)&Vld[(t*16+ln)*QP + quad*8];
      short8 bv1 = *(const short8*)&Vld[(t*16+ln)*QP + 32 + quad*8];
      accO[t] = MFMA16(ap0, bv0, accO[t], 0, 0, 0);
      accO[t] = MFMA16(ap1, bv1, accO[t], 0, 0, 0);
    }
  }

  // ---- store partials; one butterfly per block for l ----
  size_t pbase = ((size_t)(b*NT + tile)*KS + split)*4096;
  #pragma unroll
  for (int r=0;r<4;++r) {
    int n = wv*16 + quad*4 + r;
    #pragma unroll
    for (int t=0;t<4;++t)
      part[pbase + n*64 + t*16 + ln] = accO[t][r];
  }
  size_t mlb = ((size_t)(b*NT + tile)*KS + split)*64;
  #pragma unroll
  for (int r=0;r<4;++r) {
    float s = lacc[r];
    s += __shfl_xor(s, 1, 16);
    s += __shfl_xor(s, 2, 16);
    s += __shfl_xor(s, 4, 16);
    s += __shfl_xor(s, 8, 16);
    if (ln == 0) pml[mlb + wv*16 + quad*4 + r] = s;
  }
}

// Merge KS splits + out conv + residual. One block per (b, tile, half=32 rows).
__global__ __launch_bounds__(256) void attn_reduce(
    const float* __restrict__ part, const float* __restrict__ pml,
    const float* __restrict__ x, const float* __restrict__ outw,
    const float* __restrict__ outb, float* __restrict__ out)
{
  __shared__ __align__(16) float Os[32*65];
  __shared__ __align__(16) float Wot[64*65];
  __shared__ float linv[32];

  int tid = threadIdx.x;
  int blk = blockIdx.x;
  int b = blk / (NT*2);
  int rem = blk % (NT*2);
  int tile = rem >> 1, half = rem & 1;
  int nb = half*32;
  size_t base = (size_t)(b*NT + tile)*KS;

  for (int i = 0; i < 16; ++i) {
    int e = i*256 + tid; int co2 = e >> 6, c = e & 63;
    Wot[c*65 + co2] = outw[co2*64 + c];
  }
  if (tid < 32) {
    float l = 0.f;
    #pragma unroll
    for (int s=0;s<KS;++s) l += pml[(base+s)*64 + nb + tid];
    linv[tid] = 1.0f / l;
  }
  __syncthreads();

  #pragma unroll
  for (int i = 0; i < 8; ++i) {
    int e = i*256 + tid; int n = e >> 6, c = e & 63;
    float a = 0.f;
    #pragma unroll
    for (int s=0;s<KS;++s)
      a += part[(base+s)*4096 + (size_t)(nb+n)*64 + c];
    Os[n*65 + c] = a * linv[n];
  }
  __syncthreads();

  {
    int n = tid & 31, cog = tid >> 5;   // 8 groups x 8 channels
    float acc[8];
    #pragma unroll
    for (int k=0;k<8;++k) acc[k] = outb[cog*8 + k];
    for (int c = 0; c < 64; ++c) {
      float ov = Os[n*65 + c];
      #pragma unroll
      for (int k=0;k<8;++k) acc[k] += Wot[c*65 + cog*8 + k] * ov;
    }
    #pragma unroll
    for (int k=0;k<8;++k) {
      int co2 = cog*8 + k;
      int idx = (b*CH + co2)*NN + tile*64 + nb + n;
      out[idx] = acc[k] + x[idx];
    }
  }
}

extern "C" void kernel_launch(void* const* d_in, const int* in_sizes, int n_in,
                              void* d_out, int out_size, void* d_ws, size_t ws_size,
                              hipStream_t stream) {
  const float* x    = (const float*)d_in[0];
  const float* q1w  = (const float*)d_in[1];
  const float* q1g  = (const float*)d_in[2];
  const float* q1b  = (const float*)d_in[3];
  const float* q2w  = (const float*)d_in[4];
  const float* q2g  = (const float*)d_in[5];
  const float* q2b  = (const float*)d_in[6];
  const float* q3w  = (const float*)d_in[7];
  const float* q3g  = (const float*)d_in[8];
  const float* q3b  = (const float*)d_in[9];
  const float* khw  = (const float*)d_in[10];
  const float* khb  = (const float*)d_in[11];
  const float* klw  = (const float*)d_in[12];
  const float* klb  = (const float*)d_in[13];
  const float* kfw  = (const float*)d_in[14];
  const float* kfb  = (const float*)d_in[15];
  const float* vbg  = (const float*)d_in[16];
  const float* vbb  = (const float*)d_in[17];
  const float* vw   = (const float*)d_in[18];
  const float* vb   = (const float*)d_in[19];
  const float* outw = (const float*)d_in[20];
  const float* outb = (const float*)d_in[21];

  char*  wsb  = (char*)d_ws;
  float* biasf= (float*)(wsb + OFF_BIAS);
  bf16*  wh   = (bf16*)(wsb + OFF_WH_B);
  bf16*  lowg = (bf16*)(wsb + OFF_LOW_B);
  bf16*  qgT  = (bf16*)(wsb + OFF_Q_B);
  bf16*  kgT  = (bf16*)(wsb + OFF_K_B);
  bf16*  vgT  = (bf16*)(wsb + OFF_V_B);
  float* part = (float*)(wsb + OFF_P_B);
  float* pml  = (float*)(wsb + OFF_ML_B);

  hipLaunchKernelGGL(setup_fold, dim3(16), dim3(256), 0, stream,
                     q1w,q1g,q1b,q2w,q2g,q2b,q3w,q3g,q3b,
                     khw,khb,klw,klb,kfw,kfb,vbg,vbb,vw,vb, biasf, wh);
  hipLaunchKernelGGL(pool_low, dim3(BATCH*CH*NN/1024), dim3(256), 0, stream, x, lowg);
  hipLaunchKernelGGL(qkv_kernel, dim3(BATCH*NT*2), dim3(256), 0, stream,
                     x, biasf, wh, lowg, qgT, kgT, vgT);
  hipLaunchKernelGGL(attn_partial, dim3(BATCH*NT*KS), dim3(256), 0, stream,
                     qgT, kgT, vgT, part, pml);
  hipLaunchKernelGGL(attn_reduce, dim3(BATCH*NT*2), dim3(256), 0, stream,
                     part, pml, x, outw, outb, (float*)d_out);
}

// Round 8
// 177.290 us; speedup vs baseline: 4.9560x; 1.1615x over previous
//
#include <hip/hip_runtime.h>
#include <hip/hip_bf16.h>

// IRChannelAttention on MI355X. Round 8: V in [b][c][n] (no in-attn transpose,
// kills 8-way LDS write conflicts), Pld aliases Qld (27.6KB LDS -> 5 blocks/CU).
// B=2, C=64, H=W=80, N=6400. fp32 global I/O, bf16 ws intermediates.

#define BATCH 2
#define CH 64
#define HH 80
#define WW 80
#define NN 6400
#define NT 100          // NN / 64
#define KS 5            // key splits
#define KTPS (NT/KS)    // 20 key tiles per split
#define EPSV 1e-5f
#define NEGBIG (-1e30f)
#define QP 72           // bf16 LDS tile pitch (16B-aligned rows)
#define LOG2E8 0.18033688f   // log2(e)/8, folded into Q weights
#define VSP 65          // qkv V-transpose LDS pitch (odd -> 2-way banks, free)

typedef __hip_bfloat16 bf16;
typedef __attribute__((ext_vector_type(8))) short short8;   // MFMA A/B frag
typedef __attribute__((ext_vector_type(4))) float f4;       // MFMA C/D frag
#define MFMA16 __builtin_amdgcn_mfma_f32_16x16x32_bf16

__device__ __forceinline__ float b2f(bf16 v){ return __bfloat162float(v); }
__device__ __forceinline__ bf16 f2b(float v){ return __float2bfloat16(v); }
__device__ __forceinline__ float fexp2(float x){
#if __has_builtin(__builtin_amdgcn_exp2f)
  return __builtin_amdgcn_exp2f(x);
#else
  return exp2f(x);
#endif
}

// ws layout (bytes)
#define OFF_BIAS 0                         // 192 fp32: BQ(64,scaled) BK(64) BV(64)
#define OFF_WH_B 768                       // 4 x 4096 bf16: wq | wv | wa1 | wa2m
#define OFF_LOW_B (768 + 32768)            // lowg bf16 [b][c][n]
#define OFF_Q_B   (OFF_LOW_B + BATCH*CH*NN*2)   // qgT bf16 [b][n][c]
#define OFF_K_B   (OFF_Q_B   + BATCH*CH*NN*2)   // kgT bf16 [b][n][c]
#define OFF_V_B   (OFF_K_B   + BATCH*CH*NN*2)   // vgc bf16 [b][c][n]
#define OFF_P_B   (OFF_V_B   + BATCH*CH*NN*2)   // part fp32 [(b*NT+t)*KS+s][64][64]
#define OFF_ML_B  (OFF_P_B   + BATCH*NT*KS*4096*4) // l fp32 [(b*NT+t)*KS+s][64]
// total ~23.2 MB

// grid 16 x 256: one (ci,co) per thread; lane -> ci (stride-1 LDS reads),
// co wave-uniform (broadcast LDS reads). Weights staged to LDS once per block.
__global__ __launch_bounds__(256) void setup_fold(
    const float* __restrict__ q1w, const float* __restrict__ q1g, const float* __restrict__ q1b,
    const float* __restrict__ q2w, const float* __restrict__ q2g, const float* __restrict__ q2b,
    const float* __restrict__ q3w, const float* __restrict__ q3g, const float* __restrict__ q3b,
    const float* __restrict__ khw, const float* __restrict__ khb,
    const float* __restrict__ klw, const float* __restrict__ klb,
    const float* __restrict__ kfw, const float* __restrict__ kfb,
    const float* __restrict__ vg,  const float* __restrict__ vbnb,
    const float* __restrict__ vw,  const float* __restrict__ vb,
    float* __restrict__ biasf, bf16* __restrict__ wh)
{
  __shared__ __align__(16) float skf[4096];   // kfw [co][64]
  __shared__ __align__(16) float skh[2048];   // khw [j][64ci]
  __shared__ __align__(16) float skl[2048];   // klw [j][64ci]

  int tid = threadIdx.x;
  int blk = blockIdx.x;
  #pragma unroll
  for (int i = 0; i < 4; ++i)
    *(float4*)&skf[(i*256 + tid)*4] = *(const float4*)&kfw[(i*256 + tid)*4];
  #pragma unroll
  for (int i = 0; i < 2; ++i) {
    *(float4*)&skh[(i*256 + tid)*4] = *(const float4*)&khw[(i*256 + tid)*4];
    *(float4*)&skl[(i*256 + tid)*4] = *(const float4*)&klw[(i*256 + tid)*4];
  }
  __syncthreads();

  float rs = rsqrtf(1.0f + EPSV);
  bf16* wq   = wh;
  bf16* wvh  = wh + 4096;
  bf16* wa1  = wh + 8192;
  bf16* wa2m = wh + 12288;

  int t = blk*256 + tid;
  int ci = t & 63, co = t >> 6;        // co uniform per wave-half; ci = lane-fast
  int o = ci*64 + co;                  // transposed [ci][co] storage index

  float w = 0.f, g;
  if (co < 21)      { g = q1g[co];    w = (ci < 21)              ? q1w[co*21 + ci]            : 0.f; }
  else if (co < 42) { g = q2g[co-21]; w = (ci >= 21 && ci < 42)  ? q2w[(co-21)*21 + (ci-21)]  : 0.f; }
  else              { g = q3g[co-42]; w = (ci >= 42)             ? q3w[(co-42)*22 + (ci-42)]  : 0.f; }
  wq[o] = f2b(w * g * rs * LOG2E8);

  float a1 = 0.f, a2 = 0.f;
  #pragma unroll
  for (int j = 0; j < 32; ++j) {
    a1 += skf[co*64 + j]      * skh[j*64 + ci];
    a2 += skf[co*64 + 32 + j] * skl[j*64 + ci];
  }
  wa1[o]  = f2b(a1);
  wa2m[o] = f2b(a2 - a1);              // K = A1@x + (A2-A1)@low + bK
  wvh[o]  = f2b(vw[co*64 + ci] * vg[ci] * rs);

  if (blk == 0 && tid < 64) {
    int c2 = tid;
    float bq;
    if (c2 < 21)      bq = q1b[c2];
    else if (c2 < 42) bq = q2b[c2-21];
    else              bq = q3b[c2-42];
    biasf[c2] = bq * LOG2E8;
    float bk = kfb[c2];
    #pragma unroll
    for (int j = 0; j < 32; ++j) {
      bk += skf[c2*64 + j]      * khb[j];
      bk += skf[c2*64 + 32 + j] * klb[j];
    }
    biasf[64 + c2] = bk;
    float bv = vb[c2];
    for (int ci2 = 0; ci2 < 64; ++ci2) bv += vw[c2*64 + ci2] * vbnb[ci2];
    biasf[128 + c2] = bv;
  }
}

// 4 outputs/thread, aligned float4 sliding windows. grid 800.
__global__ __launch_bounds__(256) void pool_low(const float* __restrict__ x,
                                                bf16* __restrict__ lowg)
{
  int t4 = (blockIdx.x*256 + threadIdx.x)*4;
  int bc = t4 / NN; int n = t4 % NN;
  int h = n / WW, w0 = n % WW;                 // w0 multiple of 4
  const float* p = x + bc*NN;
  float m5[4], m3[4];
  #pragma unroll
  for (int j=0;j<4;++j){ m5[j]=NEGBIG; m3[j]=NEGBIG; }
  #pragma unroll
  for (int dh = -2; dh <= 2; ++dh) {
    int hh = h + dh; if (hh < 0 || hh >= HH) continue;
    float r[12];
    const float* row = p + hh*WW;
    if (w0 >= 4)      { float4 a = *(const float4*)&row[w0-4]; r[0]=a.x;r[1]=a.y;r[2]=a.z;r[3]=a.w; }
    else              { r[0]=NEGBIG;r[1]=NEGBIG;r[2]=NEGBIG;r[3]=NEGBIG; }
    { float4 a = *(const float4*)&row[w0]; r[4]=a.x;r[5]=a.y;r[6]=a.z;r[7]=a.w; }
    if (w0 + 7 < WW)  { float4 a = *(const float4*)&row[w0+4]; r[8]=a.x;r[9]=a.y;r[10]=a.z;r[11]=a.w; }
    else              { r[8]=NEGBIG;r[9]=NEGBIG;r[10]=NEGBIG;r[11]=NEGBIG; }
    bool in3 = (dh >= -1 && dh <= 1);
    #pragma unroll
    for (int j=0;j<4;++j) {
      float v3 = fmaxf(fmaxf(r[3+j], r[4+j]), r[5+j]);
      float v5 = fmaxf(fmaxf(r[2+j], v3), r[6+j]);
      m5[j] = fmaxf(m5[j], v5);
      if (in3) m3[j] = fmaxf(m3[j], v3);
    }
  }
  ushort4 o;
  o.x = ((__hip_bfloat16_raw)f2b(0.5f*(m3[0]+m5[0]))).x;
  o.y = ((__hip_bfloat16_raw)f2b(0.5f*(m3[1]+m5[1]))).x;
  o.z = ((__hip_bfloat16_raw)f2b(0.5f*(m3[2]+m5[2]))).x;
  o.w = ((__hip_bfloat16_raw)f2b(0.5f*(m3[3]+m5[3]))).x;
  *(ushort4*)&lowg[t4] = o;
}

// One block per (b, tile, half): 32 positions. Weights LDS-resident (bf16).
// Q,K stored [b][n][c] (coalesced); V transposed via LDS -> [b][c][n].
__global__ __launch_bounds__(256) void qkv_kernel(
    const float* __restrict__ x, const float* __restrict__ biasf,
    const bf16* __restrict__ wh, const bf16* __restrict__ lowg,
    bf16* __restrict__ qgT, bf16* __restrict__ kgT, bf16* __restrict__ vgc)
{
  __shared__ __align__(16) float xs[64*32];
  __shared__ __align__(16) float lows[64*32];
  __shared__ __align__(16) bf16  wbuf[16384];   // wq | wv | wa1 | wa2m
  __shared__ ushort vs[64*VSP];                 // V transpose buffer [co][p]
  __shared__ float bias[192];

  int tid = threadIdx.x;
  int blk = blockIdx.x;
  int b = blk / (NT*2);
  int rem = blk % (NT*2);
  int tile = rem >> 1, half = rem & 1;
  int n0 = tile*64 + half*32;

  #pragma unroll
  for (int i = 0; i < 8; ++i) {
    int e = i*256 + tid; int c = e >> 5, p = e & 31;
    xs[c*32 + p]   = x[(b*CH + c)*NN + n0 + p];
    lows[c*32 + p] = b2f(lowg[(b*CH + c)*NN + n0 + p]);
  }
  #pragma unroll
  for (int i = 0; i < 16; ++i)
    ((uint2*)wbuf)[i*256 + tid] = ((const uint2*)wh)[i*256 + tid];
  if (tid < 192) bias[tid] = biasf[tid];
  __syncthreads();

  int co = tid & 63, pg = tid >> 6;   // 8 positions per thread
  const bf16* wq   = wbuf;
  const bf16* wvh  = wbuf + 4096;
  const bf16* wa1  = wbuf + 8192;
  const bf16* wa2m = wbuf + 12288;

  // ---- Q (scaled, ReLU) ----
  {
    float bq = bias[co];
    float4 a0 = make_float4(bq,bq,bq,bq), a1v = a0;
    for (int ci = 0; ci < 64; ++ci) {
      float wv = b2f(wq[ci*64 + co]);
      float4 x0 = *(const float4*)&xs[ci*32 + pg*8];
      float4 x1 = *(const float4*)&xs[ci*32 + pg*8 + 4];
      a0.x += wv*x0.x; a0.y += wv*x0.y; a0.z += wv*x0.z; a0.w += wv*x0.w;
      a1v.x += wv*x1.x; a1v.y += wv*x1.y; a1v.z += wv*x1.z; a1v.w += wv*x1.w;
    }
    float q8[8] = {a0.x,a0.y,a0.z,a0.w,a1v.x,a1v.y,a1v.z,a1v.w};
    #pragma unroll
    for (int j=0;j<8;++j)
      qgT[(size_t)(b*NN + n0 + pg*8 + j)*64 + co] = f2b(fmaxf(q8[j], 0.f));
  }
  // ---- V (to LDS, then coalesced [c][n] global store) ----
  {
    float bv = bias[128 + co];
    float4 a0 = make_float4(bv,bv,bv,bv), a1v = a0;
    for (int ci = 0; ci < 64; ++ci) {
      float wv = b2f(wvh[ci*64 + co]);
      float4 x0 = *(const float4*)&xs[ci*32 + pg*8];
      float4 x1 = *(const float4*)&xs[ci*32 + pg*8 + 4];
      a0.x += wv*x0.x; a0.y += wv*x0.y; a0.z += wv*x0.z; a0.w += wv*x0.w;
      a1v.x += wv*x1.x; a1v.y += wv*x1.y; a1v.z += wv*x1.z; a1v.w += wv*x1.w;
    }
    float v8[8] = {a0.x,a0.y,a0.z,a0.w,a1v.x,a1v.y,a1v.z,a1v.w};
    #pragma unroll
    for (int j=0;j<8;++j)
      vs[co*VSP + pg*8 + j] = ((__hip_bfloat16_raw)f2b(v8[j])).x;
  }
  __syncthreads();
  {
    int c = tid >> 2, cb = (tid & 3)*8;      // channel c, 8 positions
    ushort4 o0;
    ushort u[8];
    #pragma unroll
    for (int j=0;j<8;++j) u[j] = vs[c*VSP + cb + j];
    uint4 pk;
    pk.x = (uint)u[0] | ((uint)u[1] << 16);
    pk.y = (uint)u[2] | ((uint)u[3] << 16);
    pk.z = (uint)u[4] | ((uint)u[5] << 16);
    pk.w = (uint)u[6] | ((uint)u[7] << 16);
    *(uint4*)&vgc[(size_t)(b*CH + c)*NN + n0 + cb] = pk;
    (void)o0;
  }
  // ---- K = A1@x + (A2-A1)@low + bK (one pass) ----
  {
    float bk = bias[64 + co];
    float4 a0 = make_float4(bk,bk,bk,bk), a1v = a0;
    for (int ci = 0; ci < 64; ++ci) {
      float w1 = b2f(wa1[ci*64 + co]);
      float w2 = b2f(wa2m[ci*64 + co]);
      float4 x0 = *(const float4*)&xs[ci*32 + pg*8];
      float4 x1 = *(const float4*)&xs[ci*32 + pg*8 + 4];
      float4 l0 = *(const float4*)&lows[ci*32 + pg*8];
      float4 l1 = *(const float4*)&lows[ci*32 + pg*8 + 4];
      a0.x += w1*x0.x + w2*l0.x; a0.y += w1*x0.y + w2*l0.y;
      a0.z += w1*x0.z + w2*l0.z; a0.w += w1*x0.w + w2*l0.w;
      a1v.x += w1*x1.x + w2*l1.x; a1v.y += w1*x1.y + w2*l1.y;
      a1v.z += w1*x1.z + w2*l1.z; a1v.w += w1*x1.w + w2*l1.w;
    }
    float k8[8] = {a0.x,a0.y,a0.z,a0.w,a1v.x,a1v.y,a1v.z,a1v.w};
    #pragma unroll
    for (int j=0;j<8;++j)
      kgT[(size_t)(b*NN + n0 + pg*8 + j)*64 + co] = f2b(k8[j]);
  }
}

// Split-K MFMA flash, no max-stabilizer, register l accumulation, register
// prefetch of next K/V tile. Pld aliases Qld (Q hoisted to regs). V staged
// directly from [b][c][n] global (b64 row writes, no transpose).
__global__ __launch_bounds__(256) void attn_partial(
    const bf16* __restrict__ qgT, const bf16* __restrict__ kgT, const bf16* __restrict__ vgc,
    float* __restrict__ part, float* __restrict__ pml)
{
  __shared__ __align__(16) char smem[27648];
  bf16* Qld = (bf16*)smem;              // [64][QP] n rows (dead after Q-frag hoist)
  bf16* Pld = (bf16*)smem;              // aliases Qld
  bf16* Kld = (bf16*)(smem + 9216);     // [64][QP] m rows
  bf16* Vld = (bf16*)(smem + 18432);    // [64][QP] c rows

  int tid = threadIdx.x;
  int blk = blockIdx.x;
  int b = blk / (NT*KS);
  int rem = blk % (NT*KS);
  int tile = rem / KS, split = rem % KS;
  int n0 = tile*64;
  int wv = tid >> 6, lane = tid & 63, ln = lane & 15, quad = lane >> 4;
  int arow = (wv*16 + ln)*QP;

  // stage Q [n][c], hoist frags
  #pragma unroll
  for (int i = 0; i < 4; ++i) {
    int f = (i*256 + tid)*4; int n = f >> 6, c = f & 63;
    *(uint2*)&Qld[n*QP + c] = *(const uint2*)&qgT[(size_t)(b*NN + n0 + n)*64 + c];
  }
  __syncthreads();
  short8 aq0 = *(const short8*)&Qld[arow + quad*8];
  short8 aq1 = *(const short8*)&Qld[arow + 32 + quad*8];

  f4 accO[4];
  float lacc[4];
  #pragma unroll
  for (int t=0;t<4;++t) accO[t] = (f4){0.f,0.f,0.f,0.f};
  #pragma unroll
  for (int r=0;r<4;++r) lacc[r] = 0.f;

  // prefetch tile 0 (K rows m from [n][c]; V rows c from [c][n])
  uint2 kreg[4], vreg[4];
  int mbase = split*KTPS*64;
  #pragma unroll
  for (int i = 0; i < 4; ++i) {
    int f = (i*256 + tid)*4; int rr = f >> 6, cc = f & 63;
    kreg[i] = *(const uint2*)&kgT[(size_t)(b*NN + mbase + rr)*64 + cc];
    vreg[i] = *(const uint2*)&vgc[(size_t)(b*CH + rr)*NN + mbase + cc];
  }

  for (int kt = 0; kt < KTPS; ++kt) {
    __syncthreads();   // prev iter frag reads done (also orders Q-hoist vs P writes)
    #pragma unroll
    for (int i = 0; i < 4; ++i) {
      int f = (i*256 + tid)*4; int rr = f >> 6, cc = f & 63;
      *(uint2*)&Kld[rr*QP + cc] = kreg[i];
      *(uint2*)&Vld[rr*QP + cc] = vreg[i];
    }
    __syncthreads();
    if (kt + 1 < KTPS) {
      int m0 = mbase + (kt+1)*64;
      #pragma unroll
      for (int i = 0; i < 4; ++i) {
        int f = (i*256 + tid)*4; int rr = f >> 6, cc = f & 63;
        kreg[i] = *(const uint2*)&kgT[(size_t)(b*NN + m0 + rr)*64 + cc];
        vreg[i] = *(const uint2*)&vgc[(size_t)(b*CH + rr)*NN + m0 + cc];
      }
    }

    // ---- S = Q_scaled K^T ----
    f4 accS[4];
    #pragma unroll
    for (int t = 0; t < 4; ++t) {
      short8 bk0 = *(const short8*)&Kld[(t*16+ln)*QP + quad*8];
      short8 bk1 = *(const short8*)&Kld[(t*16+ln)*QP + 32 + quad*8];
      f4 z = (f4){0.f,0.f,0.f,0.f};
      z = MFMA16(aq0, bk0, z, 0, 0, 0);
      accS[t] = MFMA16(aq1, bk1, z, 0, 0, 0);
    }

    // ---- P = exp2(S); l accumulates in registers (no cross-lane ops) ----
    #pragma unroll
    for (int r=0;r<4;++r) {
      int n = wv*16 + quad*4 + r;
      #pragma unroll
      for (int t=0;t<4;++t) {
        float p = fexp2(accS[t][r]);
        Pld[n*QP + t*16 + ln] = f2b(p);
        lacc[r] += p;
      }
    }

    // ---- O += P V^T (P wave-local; per-wave DS ordering suffices) ----
    short8 ap0 = *(const short8*)&Pld[arow + quad*8];
    short8 ap1 = *(const short8*)&Pld[arow + 32 + quad*8];
    #pragma unroll
    for (int t = 0; t < 4; ++t) {
      short8 bv0 = *(const short8*)&Vld[(t*16+ln)*QP + quad*8];
      short8 bv1 = *(const short8*)&Vld[(t*16+ln)*QP + 32 + quad*8];
      accO[t] = MFMA16(ap0, bv0, accO[t], 0, 0, 0);
      accO[t] = MFMA16(ap1, bv1, accO[t], 0, 0, 0);
    }
  }

  // ---- store partials; one butterfly per block for l ----
  size_t pbase = ((size_t)(b*NT + tile)*KS + split)*4096;
  #pragma unroll
  for (int r=0;r<4;++r) {
    int n = wv*16 + quad*4 + r;
    #pragma unroll
    for (int t=0;t<4;++t)
      part[pbase + n*64 + t*16 + ln] = accO[t][r];
  }
  size_t mlb = ((size_t)(b*NT + tile)*KS + split)*64;
  #pragma unroll
  for (int r=0;r<4;++r) {
    float s = lacc[r];
    s += __shfl_xor(s, 1, 16);
    s += __shfl_xor(s, 2, 16);
    s += __shfl_xor(s, 4, 16);
    s += __shfl_xor(s, 8, 16);
    if (ln == 0) pml[mlb + wv*16 + quad*4 + r] = s;
  }
}

// Merge KS splits + out conv + residual. One block per (b, tile, half=32 rows).
__global__ __launch_bounds__(256) void attn_reduce(
    const float* __restrict__ part, const float* __restrict__ pml,
    const float* __restrict__ x, const float* __restrict__ outw,
    const float* __restrict__ outb, float* __restrict__ out)
{
  __shared__ __align__(16) float Os[32*65];
  __shared__ __align__(16) float Wot[64*65];
  __shared__ float linv[32];

  int tid = threadIdx.x;
  int blk = blockIdx.x;
  int b = blk / (NT*2);
  int rem = blk % (NT*2);
  int tile = rem >> 1, half = rem & 1;
  int nb = half*32;
  size_t base = (size_t)(b*NT + tile)*KS;

  for (int i = 0; i < 16; ++i) {
    int e = i*256 + tid; int co2 = e >> 6, c = e & 63;
    Wot[c*65 + co2] = outw[co2*64 + c];
  }
  if (tid < 32) {
    float l = 0.f;
    #pragma unroll
    for (int s=0;s<KS;++s) l += pml[(base+s)*64 + nb + tid];
    linv[tid] = 1.0f / l;
  }
  __syncthreads();

  #pragma unroll
  for (int i = 0; i < 8; ++i) {
    int e = i*256 + tid; int n = e >> 6, c = e & 63;
    float a = 0.f;
    #pragma unroll
    for (int s=0;s<KS;++s)
      a += part[(base+s)*4096 + (size_t)(nb+n)*64 + c];
    Os[n*65 + c] = a * linv[n];
  }
  __syncthreads();

  {
    int n = tid & 31, cog = tid >> 5;   // 8 groups x 8 channels
    float acc[8];
    #pragma unroll
    for (int k=0;k<8;++k) acc[k] = outb[cog*8 + k];
    for (int c = 0; c < 64; ++c) {
      float ov = Os[n*65 + c];
      #pragma unroll
      for (int k=0;k<8;++k) acc[k] += Wot[c*65 + cog*8 + k] * ov;
    }
    #pragma unroll
    for (int k=0;k<8;++k) {
      int co2 = cog*8 + k;
      int idx = (b*CH + co2)*NN + tile*64 + nb + n;
      out[idx] = acc[k] + x[idx];
    }
  }
}

extern "C" void kernel_launch(void* const* d_in, const int* in_sizes, int n_in,
                              void* d_out, int out_size, void* d_ws, size_t ws_size,
                              hipStream_t stream) {
  const float* x    = (const float*)d_in[0];
  const float* q1w  = (const float*)d_in[1];
  const float* q1g  = (const float*)d_in[2];
  const float* q1b  = (const float*)d_in[3];
  const float* q2w  = (const float*)d_in[4];
  const float* q2g  = (const float*)d_in[5];
  const float* q2b  = (const float*)d_in[6];
  const float* q3w  = (const float*)d_in[7];
  const float* q3g  = (const float*)d_in[8];
  const float* q3b  = (const float*)d_in[9];
  const float* khw  = (const float*)d_in[10];
  const float* khb  = (const float*)d_in[11];
  const float* klw  = (const float*)d_in[12];
  const float* klb  = (const float*)d_in[13];
  const float* kfw  = (const float*)d_in[14];
  const float* kfb  = (const float*)d_in[15];
  const float* vbg  = (const float*)d_in[16];
  const float* vbb  = (const float*)d_in[17];
  const float* vw   = (const float*)d_in[18];
  const float* vb   = (const float*)d_in[19];
  const float* outw = (const float*)d_in[20];
  const float* outb = (const float*)d_in[21];

  char*  wsb  = (char*)d_ws;
  float* biasf= (float*)(wsb + OFF_BIAS);
  bf16*  wh   = (bf16*)(wsb + OFF_WH_B);
  bf16*  lowg = (bf16*)(wsb + OFF_LOW_B);
  bf16*  qgT  = (bf16*)(wsb + OFF_Q_B);
  bf16*  kgT  = (bf16*)(wsb + OFF_K_B);
  bf16*  vgc  = (bf16*)(wsb + OFF_V_B);
  float* part = (float*)(wsb + OFF_P_B);
  float* pml  = (float*)(wsb + OFF_ML_B);

  hipLaunchKernelGGL(setup_fold, dim3(16), dim3(256), 0, stream,
                     q1w,q1g,q1b,q2w,q2g,q2b,q3w,q3g,q3b,
                     khw,khb,klw,klb,kfw,kfb,vbg,vbb,vw,vb, biasf, wh);
  hipLaunchKernelGGL(pool_low, dim3(BATCH*CH*NN/1024), dim3(256), 0, stream, x, lowg);
  hipLaunchKernelGGL(qkv_kernel, dim3(BATCH*NT*2), dim3(256), 0, stream,
                     x, biasf, wh, lowg, qgT, kgT, vgc);
  hipLaunchKernelGGL(attn_partial, dim3(BATCH*NT*KS), dim3(256), 0, stream,
                     qgT, kgT, vgc, part, pml);
  hipLaunchKernelGGL(attn_reduce, dim3(BATCH*NT*2), dim3(256), 0, stream,
                     part, pml, x, outw, outb, (float*)d_out);
}